// Round 2
// baseline (9844.107 us; speedup 1.0000x reference)
//
#include <hip/hip_runtime.h>
#include <hip/hip_bf16.h>
#include <math.h>

#define NV 50000
#define NE 256
#define NH 256
#define NT 20
#define NB 64
#define NL 512
#define TAG_START 18
#define TAG_STOP 19
#define NEGV -10000.0f

__device__ __forceinline__ float sigf(float x) { return 1.0f / (1.0f + expf(-x)); }

// ---------------------------------------------------------------------------
// K0: transpose four 1024x256 weight matrices -> 256x1024 for coalesced GEMV
// ---------------------------------------------------------------------------
__global__ __launch_bounds__(256) void k_transpose(
    const float* __restrict__ whh_f, const float* __restrict__ whh_b,
    const float* __restrict__ wih_f, const float* __restrict__ wih_b,
    float* __restrict__ thh_f, float* __restrict__ thh_b,
    float* __restrict__ tih_f, float* __restrict__ tih_b)
{
    int e = blockIdx.x * 256 + threadIdx.x;     // 0 .. 262143
    const float* w; float* wt;
    switch (blockIdx.y) {
        case 0: w = whh_f; wt = thh_f; break;
        case 1: w = whh_b; wt = thh_b; break;
        case 2: w = wih_f; wt = tih_f; break;
        default: w = wih_b; wt = tih_b; break;
    }
    int n = e >> 8, k = e & 255;                 // w[n][k]  (n<1024, k<256)
    wt[k * 1024 + n] = w[e];
}

// ---------------------------------------------------------------------------
// K1: fully fused recurrent LSTM + emissions.
//     One WG per (batch, direction), 1024 threads.
//     Per step: g = x_t @ Wih^T + h @ Whh^T + bias  (thread n -> gate n)
//               pointwise -> h, c (threads < 256)
//               emissions partial: scores_dir[b,t,tag] = h . w_out[tag, dirslice]
// ---------------------------------------------------------------------------
__global__ __launch_bounds__(1024) void k_rec(
    const int* __restrict__ sent, const int* __restrict__ lens,
    const float* __restrict__ emb,
    const float* __restrict__ thh_f, const float* __restrict__ thh_b,
    const float* __restrict__ tih_f, const float* __restrict__ tih_b,
    const float* __restrict__ b_ih_f, const float* __restrict__ b_hh_f,
    const float* __restrict__ b_ih_b, const float* __restrict__ b_hh_b,
    const float* __restrict__ w_out,
    float* __restrict__ sc_f, float* __restrict__ sc_b)
{
    const int b   = blockIdx.x;
    const int dir = blockIdx.y;
    const int len = lens[b];
    const int n   = threadIdx.x;

    const float* Whh = dir ? thh_b : thh_f;   // [k][n] = [256][1024]
    const float* Wih = dir ? tih_b : tih_f;
    const float* bi  = dir ? b_ih_b : b_ih_f;
    const float* bh  = dir ? b_hh_b : b_hh_f;
    float* scout = dir ? sc_b : sc_f;

    __shared__ float x_s[256];
    __shared__ float h_s[256];
    __shared__ float g_s[1024];
    __shared__ float bias_s[1024];
    __shared__ float wout_s[20 * 257];
    __shared__ float part_s[20][8];

    bias_s[n] = bi[n] + bh[n];
    for (int e = n; e < 20 * 256; e += 1024)
        wout_s[(e >> 8) * 257 + (e & 255)] = w_out[(e >> 8) * 512 + dir * 256 + (e & 255)];
    if (n < 256) h_s[n] = 0.0f;
    float c = 0.0f;
    __syncthreads();

    const int sbase = b << 9;
    for (int t = 0; t < len; ++t) {
        // stage x_t (embedding row; reversed index for backward direction)
        if (n < 256) {
            int ti  = dir ? (len - 1 - t) : t;
            int tok = sent[sbase + ti];
            x_s[n] = emb[(size_t)tok * NE + n];
        }
        __syncthreads();

        // gate n = bias + x.Wih[:,n] + h.Whh[:,n]
        float acc = bias_s[n];
        const float* wi = Wih + n;
        const float* wh = Whh + n;
#pragma unroll 8
        for (int k = 0; k < 256; ++k) {
            acc = fmaf(wh[(size_t)(k << 10)], h_s[k], acc);
            acc = fmaf(wi[(size_t)(k << 10)], x_s[k], acc);
        }
        g_s[n] = acc;
        __syncthreads();

        // pointwise LSTM cell
        if (n < 256) {
            float ig = g_s[n], fg = g_s[n + 256], gg = g_s[n + 512], og = g_s[n + 768];
            float cn = sigf(fg) * c + sigf(ig) * tanhf(gg);
            float hn = sigf(og) * tanhf(cn);
            c = cn;
            h_s[n] = hn;
        }
        __syncthreads();

        // emissions partial: 160 threads, tag = n>>3, slice = n&7
        if (n < 160) {
            const int tag = n >> 3, sl = n & 7;
            const float* wrow = wout_s + tag * 257;
            float s = 0.0f;
#pragma unroll 8
            for (int j = 0; j < 32; ++j) {
                int k = sl + (j << 3);
                s = fmaf(wrow[k], h_s[k], s);
            }
            part_s[tag][sl] = s;
        }
        __syncthreads();

        if (n < 20) {
            float s = part_s[n][0];
#pragma unroll
            for (int j = 1; j < 8; ++j) s += part_s[n][j];
            int tp = dir ? (len - 1 - t) : t;
            scout[(size_t)(sbase + tp) * 20 + n] = s;
        }
        // no sync needed here: next-iter writes touch x_s only, ordered by the
        // sync after the x-stage; part_s is rewritten only after 3 more syncs
    }
}

// ---------------------------------------------------------------------------
// K2: Viterbi forward + backtrack. One wave per batch element.
//     scores[b,t,tag] = sc_f + sc_b + b_out  (summed on the fly)
// ---------------------------------------------------------------------------
__global__ __launch_bounds__(64) void k_viterbi(
    const int* __restrict__ lens,
    const float* __restrict__ sc_f, const float* __restrict__ sc_b,
    const float* __restrict__ b_out, const float* __restrict__ trans,
    float* __restrict__ out)
{
    const int b = blockIdx.x;
    const int lane = threadIdx.x;
    const int len = lens[b];

    __shared__ float tr_s[20][21];
    __shared__ float fv_s[20];
    __shared__ float term_s[20];
    __shared__ float bo_s[20];
    __shared__ unsigned char bp_s[512][20];
    __shared__ unsigned char path_s[512];

    for (int e = lane; e < 400; e += 64) tr_s[e / 20][e % 20] = trans[e];
    if (lane < 20) {
        fv_s[lane] = (lane == TAG_START) ? 0.0f : NEGV;
        bo_s[lane] = b_out[lane];
    }
    __syncthreads();

    const size_t sb = (size_t)(b << 9) * 20;
    for (int t = 0; t < len; ++t) {
        float m = 0.0f; int arg = 0;
        if (lane < 20) {
            m = fv_s[0] + tr_s[lane][0]; arg = 0;
#pragma unroll
            for (int k = 1; k < 20; ++k) {
                float v = fv_s[k] + tr_s[lane][k];
                if (v > m) { m = v; arg = k; }        // first-max (jnp.argmax)
            }
            m += sc_f[sb + t * 20 + lane] + sc_b[sb + t * 20 + lane] + bo_s[lane];
        }
        __syncthreads();
        if (lane < 20) { fv_s[lane] = m; bp_s[t][lane] = (unsigned char)arg; }
        __syncthreads();
    }

    if (lane < 20) term_s[lane] = fv_s[lane] + tr_s[TAG_STOP][lane];
    __syncthreads();

    if (lane == 0) {
        float m = term_s[0]; int arg = 0;
        for (int k = 1; k < 20; ++k) if (term_s[k] > m) { m = term_s[k]; arg = k; }
        out[b] = m;                                   // path score
        int cur = arg;
        path_s[len - 1] = (unsigned char)cur;
        for (int j = len - 1; j >= 1; --j) {
            cur = bp_s[j][cur];
            path_s[j - 1] = (unsigned char)cur;
        }
    }
    __syncthreads();

    float* po = out + NB + ((size_t)b << 9);
    for (int p = lane; p < NL; p += 64) po[p] = (p < len) ? (float)path_s[p] : 0.0f;
}

// ---------------------------------------------------------------------------
extern "C" void kernel_launch(void* const* d_in, const int* in_sizes, int n_in,
                              void* d_out, int out_size, void* d_ws, size_t ws_size,
                              hipStream_t stream)
{
    const int*   sent    = (const int*)d_in[0];
    const int*   lens    = (const int*)d_in[1];
    const float* emb     = (const float*)d_in[2];
    const float* w_ih_f  = (const float*)d_in[3];
    const float* w_hh_f  = (const float*)d_in[4];
    const float* b_ih_f  = (const float*)d_in[5];
    const float* b_hh_f  = (const float*)d_in[6];
    const float* w_ih_b  = (const float*)d_in[7];
    const float* w_hh_b  = (const float*)d_in[8];
    const float* b_ih_b  = (const float*)d_in[9];
    const float* b_hh_b  = (const float*)d_in[10];
    const float* w_out   = (const float*)d_in[11];
    const float* b_out   = (const float*)d_in[12];
    const float* trans   = (const float*)d_in[13];

    // workspace: 4 transposed weight mats (1 MB each) + 2 score buffers (2.5 MB each)
    float* ws    = (float*)d_ws;
    float* thh_f = ws;                          // 256*1024
    float* thh_b = thh_f + 262144;
    float* tih_f = thh_b + 262144;
    float* tih_b = tih_f + 262144;
    float* sc_f  = tih_b + 262144;              // 64*512*20
    float* sc_b  = sc_f + (size_t)NB * NL * NT;
    // total: 2,359,296 floats = 9.44 MB

    k_transpose<<<dim3(1024, 4), 256, 0, stream>>>(
        w_hh_f, w_hh_b, w_ih_f, w_ih_b, thh_f, thh_b, tih_f, tih_b);

    k_rec<<<dim3(NB, 2), 1024, 0, stream>>>(
        sent, lens, emb, thh_f, thh_b, tih_f, tih_b,
        b_ih_f, b_hh_f, b_ih_b, b_hh_b, w_out, sc_f, sc_b);

    k_viterbi<<<NB, 64, 0, stream>>>(lens, sc_f, sc_b, b_out, trans, (float*)d_out);
}

// Round 3
// 5842.355 us; speedup vs baseline: 1.6850x; 1.6850x over previous
//
#include <hip/hip_runtime.h>
#include <hip/hip_bf16.h>
#include <math.h>

#define NV 50000
#define NE 256
#define NH 256
#define NT 20
#define NB 64
#define NL 512
#define TAG_START 18
#define TAG_STOP 19
#define NEGV -10000.0f

typedef unsigned short ushortT;
typedef __attribute__((ext_vector_type(4))) float f32x4;
typedef __attribute__((ext_vector_type(8))) short short8;

__device__ __forceinline__ float sigf_slow(float x) { return 1.0f / (1.0f + expf(-x)); }
__device__ __forceinline__ float fsig(float x) { return 1.0f / (1.0f + __expf(-x)); }
__device__ __forceinline__ float ftanh(float x) { return 1.0f - 2.0f / (1.0f + __expf(2.0f * x)); }
__device__ __forceinline__ ushortT f2bf(float f) {
    unsigned int u = __float_as_uint(f);
    u += 0x7fffu + ((u >> 16) & 1u);
    return (ushortT)(u >> 16);
}
__device__ __forceinline__ float bf2f(unsigned int bits16) {
    return __uint_as_float(bits16 << 16);
}

// ===========================================================================
// FAST PATH
// ===========================================================================

// K-cvt: fp32 -> bf16 for the four weight matrices [1024][256]
__global__ __launch_bounds__(256) void k_cvtw(
    const float* __restrict__ whh_f, const float* __restrict__ whh_b,
    const float* __restrict__ wih_f, const float* __restrict__ wih_b,
    ushortT* __restrict__ whh16, ushortT* __restrict__ wih16)
{
    int idx = blockIdx.x * 256 + threadIdx.x;     // < 262144
    const float* s; ushortT* d;
    switch (blockIdx.y) {
        case 0: s = whh_f; d = whh16;            break;
        case 1: s = whh_b; d = whh16 + 262144;   break;
        case 2: s = wih_f; d = wih16;            break;
        default: s = wih_b; d = wih16 + 262144;  break;
    }
    d[idx] = f2bf(s[idx]);
}

__global__ __launch_bounds__(1024) void k_bias(
    const float* __restrict__ bih_f, const float* __restrict__ bhh_f,
    const float* __restrict__ bih_b, const float* __restrict__ bhh_b,
    float* __restrict__ biasc)
{
    int n = threadIdx.x;
    if (blockIdx.x == 0) biasc[n] = bih_f[n] + bhh_f[n];
    else                 biasc[1024 + n] = bih_b[n] + bhh_b[n];
}

// K-gin: gin[dir][group][tt][frag-layout] = x_t @ Wih^T + bias  (bf16 MFMA)
// WG = 512 thr (8 waves); wave w owns unit-interleaved col-tiles.
__global__ __launch_bounds__(512, 1) void k_gin_mfma(
    const int* __restrict__ sent, const int* __restrict__ lens,
    const float* __restrict__ emb, const ushortT* __restrict__ wih16,
    const float* __restrict__ biasc, float* __restrict__ gin,
    int chunk_start, int CH)
{
    const int g = blockIdx.x, tsub = blockIdx.y, dir = blockIdx.z;
    const int gmax = lens[g * 16];
    const int tt0 = tsub * 16;
    if (chunk_start + tt0 >= gmax) return;

    const int tid = threadIdx.x;
    const int w = tid >> 6, l = tid & 63, lr = l & 15, lg = l >> 4;

    __shared__ char x_raw[16 * 512];

    // B fragments (Wih^T), resident in VGPRs, reused for 16 timesteps
    short8 bfr[8][8];
    float bias_l[8];
    const ushortT* wsrc = wih16 + dir * 262144;
#pragma unroll
    for (int nt = 0; nt < 8; ++nt) {
        int col = (nt >> 1) * 256 + w * 32 + (nt & 1) * 16 + lr;
        bias_l[nt] = biasc[dir * 1024 + col];
#pragma unroll
        for (int kt = 0; kt < 8; ++kt)
            bfr[nt][kt] = *(const short8*)(wsrc + col * 256 + kt * 32 + lg * 8);
    }

    const int srow = tid >> 5, sseg = tid & 31;
    const int slen = lens[g * 16 + srow];
    const int sb = (g * 16 + srow) * 512;

    for (int i = 0; i < 16; ++i) {
        int tg = chunk_start + tt0 + i;
        if (tg >= gmax) break;

        // stage x_t: 16 rows x 256 fp32 -> bf16, swizzled LDS
        int tsrc = dir ? (slen - 1 - tg) : tg;
        if (tsrc < 0) tsrc = 0;
        if (tsrc > 511) tsrc = 511;
        int tok = sent[sb + tsrc];
        const float* es = emb + (size_t)tok * 256 + sseg * 8;
        float4 e0 = *(const float4*)es;
        float4 e1 = *(const float4*)(es + 4);
        short8 xv;
        xv[0] = (short)f2bf(e0.x); xv[1] = (short)f2bf(e0.y);
        xv[2] = (short)f2bf(e0.z); xv[3] = (short)f2bf(e0.w);
        xv[4] = (short)f2bf(e1.x); xv[5] = (short)f2bf(e1.y);
        xv[6] = (short)f2bf(e1.z); xv[7] = (short)f2bf(e1.w);
        int sa = (srow * 512 + sseg * 16) ^ ((srow & 7) << 4);
        *(short8*)&x_raw[sa] = xv;
        __syncthreads();

        // A fragments + MFMA
        short8 af[8];
#pragma unroll
        for (int kt = 0; kt < 8; ++kt) {
            int a = (lr * 512 + kt * 64 + lg * 16) ^ ((lr & 7) << 4);
            af[kt] = *(const short8*)&x_raw[a];
        }
        f32x4 acc[8];
#pragma unroll
        for (int nt = 0; nt < 8; ++nt) {
            acc[nt][0] = bias_l[nt]; acc[nt][1] = bias_l[nt];
            acc[nt][2] = bias_l[nt]; acc[nt][3] = bias_l[nt];
        }
#pragma unroll
        for (int nt = 0; nt < 8; ++nt)
#pragma unroll
            for (int kt = 0; kt < 8; ++kt)
                acc[nt] = __builtin_amdgcn_mfma_f32_16x16x32_bf16(af[kt], bfr[nt][kt], acc[nt], 0, 0, 0);

        // store in frag layout: 64 lanes x 16B contiguous per frag
        float* ginp = gin + ((size_t)((dir * 4 + g) * CH + (tt0 + i))) * 16384;
#pragma unroll
        for (int nt = 0; nt < 8; ++nt)
            *(f32x4*)(ginp + (w * 8 + nt) * 256 + l * 4) = acc[nt];
        __syncthreads();
    }
}

// K-rec: weight-stationary MFMA recurrence. One WG (8 waves) per (group, dir).
__global__ __launch_bounds__(512, 1) void k_rec_mfma(
    const int* __restrict__ lens, const ushortT* __restrict__ whh16,
    const float* __restrict__ gin, ushortT* __restrict__ hout,
    ushortT* __restrict__ st_h, float* __restrict__ st_c,
    int chunk_start, int CH)
{
    const int g = blockIdx.x, dir = blockIdx.y;
    const int gmax = lens[g * 16];
    const int nsteps = min(CH, gmax - chunk_start);
    if (nsteps <= 0) return;

    const int tid = threadIdx.x;
    const int w = tid >> 6, l = tid & 63, lr = l & 15, lg = l >> 4;

    __shared__ char h_raw[16 * 512];

    int lenr[4];
#pragma unroll
    for (int r = 0; r < 4; ++r) lenr[r] = lens[g * 16 + lg * 4 + r];

    // B fragments (Whh^T): 256 VGPRs, loaded once for the whole chunk
    short8 bfr[8][8];
    const ushortT* wsrc = whh16 + dir * 262144;
#pragma unroll
    for (int nt = 0; nt < 8; ++nt) {
        int col = (nt >> 1) * 256 + w * 32 + (nt & 1) * 16 + lr;
#pragma unroll
        for (int kt = 0; kt < 8; ++kt)
            bfr[nt][kt] = *(const short8*)(wsrc + col * 256 + kt * 32 + lg * 8);
    }

    // state init / restore
    float c[2][4];
    if (chunk_start == 0) {
#pragma unroll
        for (int ut = 0; ut < 2; ++ut)
#pragma unroll
            for (int r = 0; r < 4; ++r) c[ut][r] = 0.0f;
        for (int i = tid; i < 2048; i += 512) ((int*)h_raw)[i] = 0;
    } else {
        const float* cs = st_c + ((size_t)((dir * 4 + g) * 512 + tid)) * 8;
#pragma unroll
        for (int ut = 0; ut < 2; ++ut)
#pragma unroll
            for (int r = 0; r < 4; ++r) c[ut][r] = cs[ut * 4 + r];
        const int* hs = (const int*)(st_h + (dir * 4 + g) * 4096);
        for (int i = tid; i < 2048; i += 512) ((int*)h_raw)[i] = hs[i];
    }
    __syncthreads();

    const float* ginp = gin + ((size_t)((dir * 4 + g) * CH)) * 16384;
    f32x4 cur[8];
#pragma unroll
    for (int nt = 0; nt < 8; ++nt)
        cur[nt] = *(const f32x4*)(ginp + (w * 8 + nt) * 256 + l * 4);

    for (int tt = 0; tt < nsteps; ++tt) {
        const int t_glob = chunk_start + tt;

        f32x4 acc[8];
#pragma unroll
        for (int nt = 0; nt < 8; ++nt) acc[nt] = cur[nt];

        if (tt + 1 < nsteps) {
            const float* gp2 = ginp + (size_t)(tt + 1) * 16384;
#pragma unroll
            for (int nt = 0; nt < 8; ++nt)
                cur[nt] = *(const f32x4*)(gp2 + (w * 8 + nt) * 256 + l * 4);
        }

        // A fragments: h_t from swizzled LDS
        short8 af[8];
#pragma unroll
        for (int kt = 0; kt < 8; ++kt) {
            int a = (lr * 512 + kt * 64 + lg * 16) ^ ((lr & 7) << 4);
            af[kt] = *(const short8*)&h_raw[a];
        }
#pragma unroll
        for (int nt = 0; nt < 8; ++nt)
#pragma unroll
            for (int kt = 0; kt < 8; ++kt)
                acc[nt] = __builtin_amdgcn_mfma_f32_16x16x32_bf16(af[kt], bfr[nt][kt], acc[nt], 0, 0, 0);

        __syncthreads();   // all A-reads of h_raw complete before overwrite

        // pointwise LSTM cell, entirely in registers
#pragma unroll
        for (int ut = 0; ut < 2; ++ut) {
            const int unit = w * 32 + ut * 16 + lr;
#pragma unroll
            for (int r = 0; r < 4; ++r) {
                float i_ = acc[0 + ut][r];
                float f_ = acc[2 + ut][r];
                float g_ = acc[4 + ut][r];
                float o_ = acc[6 + ut][r];
                float cn = fsig(f_) * c[ut][r] + fsig(i_) * ftanh(g_);
                float hn = fsig(o_) * ftanh(cn);
                c[ut][r] = cn;
                ushortT hb = f2bf(hn);
                const int row = lg * 4 + r;
                int a = (row * 512 + unit * 2) ^ ((row & 7) << 4);
                *(ushortT*)&h_raw[a] = hb;
                if (t_glob < lenr[r]) {
                    int tp = dir ? (lenr[r] - 1 - t_glob) : t_glob;
                    int brow = g * 16 + row;
                    hout[((size_t)(brow * 512 + tp)) * 512 + dir * 256 + unit] = hb;
                }
            }
        }
        __syncthreads();   // h_{t+1} visible before next A-reads
    }

    // save state
    float* cs = st_c + ((size_t)((dir * 4 + g) * 512 + tid)) * 8;
#pragma unroll
    for (int ut = 0; ut < 2; ++ut)
#pragma unroll
        for (int r = 0; r < 4; ++r) cs[ut * 4 + r] = c[ut][r];
    int* hs = (int*)(st_h + (dir * 4 + g) * 4096);
    for (int i = tid; i < 2048; i += 512) hs[i] = ((int*)h_raw)[i];
}

// K-scores: scores[b,t,:] = h[b,t,:] (bf16) @ w_out^T + b_out  (t < len)
__global__ __launch_bounds__(256) void k_scores_bf(
    const int* __restrict__ lens, const ushortT* __restrict__ hout,
    const float* __restrict__ w_out, const float* __restrict__ b_out,
    float* __restrict__ scores)
{
    const int b = blockIdx.y;
    const int t0 = blockIdx.x * 32;
    const int len = lens[b];
    if (t0 >= len) return;

    __shared__ float w_s[20 * 513];
    __shared__ float row_s[512];
    __shared__ float part_s[20][9];
    __shared__ float bo_s[20];

    const int tid = threadIdx.x;
    for (int e = tid; e < 20 * 512; e += 256) w_s[(e >> 9) * 513 + (e & 511)] = w_out[e];
    if (tid < 20) bo_s[tid] = b_out[tid];
    __syncthreads();

    const int tend = min(t0 + 32, len);
    const int tag = tid >> 3, sl = tid & 7;
    for (int t = t0; t < tend; ++t) {
        const ushortT* hr = hout + ((size_t)(b * 512 + t)) * 512;
        unsigned int v = ((const unsigned int*)hr)[tid];
        row_s[tid * 2] = bf2f(v & 0xffffu);
        row_s[tid * 2 + 1] = bf2f(v >> 16);
        __syncthreads();
        if (tid < 160) {
            float s = 0.0f;
#pragma unroll 8
            for (int j = 0; j < 64; ++j) {
                int k = sl + (((j + tag) & 63) << 3);
                s = fmaf(w_s[tag * 513 + k], row_s[k], s);
            }
            part_s[tag][sl] = s;
        }
        __syncthreads();
        if (tid < 20) {
            float s = bo_s[tid];
#pragma unroll
            for (int j = 0; j < 8; ++j) s += part_s[tid][j];
            scores[((size_t)(b * 512 + t)) * 20 + tid] = s;
        }
        __syncthreads();
    }
}

// K-viterbi (single combined scores buffer, b_out already included)
__global__ __launch_bounds__(64) void k_viterbi_s(
    const int* __restrict__ lens, const float* __restrict__ scores,
    const float* __restrict__ trans, float* __restrict__ out)
{
    const int b = blockIdx.x;
    const int lane = threadIdx.x;
    const int len = lens[b];

    __shared__ float tr_s[20][21];
    __shared__ float fv_s[20];
    __shared__ float term_s[20];
    __shared__ unsigned char bp_s[512][20];
    __shared__ unsigned char path_s[512];

    for (int e = lane; e < 400; e += 64) tr_s[e / 20][e % 20] = trans[e];
    if (lane < 20) fv_s[lane] = (lane == TAG_START) ? 0.0f : NEGV;
    __syncthreads();

    const float* sc = scores + ((size_t)(b << 9)) * 20;
    for (int t = 0; t < len; ++t) {
        float m = 0.0f; int arg = 0;
        if (lane < 20) {
            m = fv_s[0] + tr_s[lane][0]; arg = 0;
#pragma unroll
            for (int k = 1; k < 20; ++k) {
                float v = fv_s[k] + tr_s[lane][k];
                if (v > m) { m = v; arg = k; }
            }
            m += sc[t * 20 + lane];
        }
        __syncthreads();
        if (lane < 20) { fv_s[lane] = m; bp_s[t][lane] = (unsigned char)arg; }
        __syncthreads();
    }

    if (lane < 20) term_s[lane] = fv_s[lane] + tr_s[TAG_STOP][lane];
    __syncthreads();

    if (lane == 0) {
        float m = term_s[0]; int arg = 0;
        for (int k = 1; k < 20; ++k) if (term_s[k] > m) { m = term_s[k]; arg = k; }
        out[b] = m;
        int cur = arg;
        path_s[len - 1] = (unsigned char)cur;
        for (int j = len - 1; j >= 1; --j) {
            cur = bp_s[j][cur];
            path_s[j - 1] = (unsigned char)cur;
        }
    }
    __syncthreads();

    float* po = out + NB + ((size_t)b << 9);
    for (int p = lane; p < NL; p += 64) po[p] = (p < len) ? (float)path_s[p] : 0.0f;
}

// ===========================================================================
// FALLBACK PATH (round-2, proven) — used only if ws_size is too small
// ===========================================================================
__global__ __launch_bounds__(256) void k_transpose_fb(
    const float* __restrict__ whh_f, const float* __restrict__ whh_b,
    const float* __restrict__ wih_f, const float* __restrict__ wih_b,
    float* __restrict__ thh_f, float* __restrict__ thh_b,
    float* __restrict__ tih_f, float* __restrict__ tih_b)
{
    int e = blockIdx.x * 256 + threadIdx.x;
    const float* wm; float* wt;
    switch (blockIdx.y) {
        case 0: wm = whh_f; wt = thh_f; break;
        case 1: wm = whh_b; wt = thh_b; break;
        case 2: wm = wih_f; wt = tih_f; break;
        default: wm = wih_b; wt = tih_b; break;
    }
    int n = e >> 8, k = e & 255;
    wt[k * 1024 + n] = wm[e];
}

__global__ __launch_bounds__(1024) void k_rec_fb(
    const int* __restrict__ sent, const int* __restrict__ lens,
    const float* __restrict__ emb,
    const float* __restrict__ thh_f, const float* __restrict__ thh_b,
    const float* __restrict__ tih_f, const float* __restrict__ tih_b,
    const float* __restrict__ b_ih_f, const float* __restrict__ b_hh_f,
    const float* __restrict__ b_ih_b, const float* __restrict__ b_hh_b,
    const float* __restrict__ w_out,
    float* __restrict__ sc_f, float* __restrict__ sc_b)
{
    const int b = blockIdx.x, dir = blockIdx.y;
    const int len = lens[b];
    const int n = threadIdx.x;
    const float* Whh = dir ? thh_b : thh_f;
    const float* Wih = dir ? tih_b : tih_f;
    const float* bi = dir ? b_ih_b : b_ih_f;
    const float* bh = dir ? b_hh_b : b_hh_f;
    float* scout = dir ? sc_b : sc_f;

    __shared__ float x_s[256];
    __shared__ float h_s[256];
    __shared__ float g_s[1024];
    __shared__ float bias_s[1024];
    __shared__ float wout_s[20 * 257];
    __shared__ float part_s[20][8];

    bias_s[n] = bi[n] + bh[n];
    for (int e = n; e < 20 * 256; e += 1024)
        wout_s[(e >> 8) * 257 + (e & 255)] = w_out[(e >> 8) * 512 + dir * 256 + (e & 255)];
    if (n < 256) h_s[n] = 0.0f;
    float c = 0.0f;
    __syncthreads();

    const int sbase = b << 9;
    for (int t = 0; t < len; ++t) {
        if (n < 256) {
            int ti = dir ? (len - 1 - t) : t;
            int tok = sent[sbase + ti];
            x_s[n] = emb[(size_t)tok * NE + n];
        }
        __syncthreads();
        float acc = bias_s[n];
        const float* wi = Wih + n;
        const float* wh = Whh + n;
#pragma unroll 8
        for (int k = 0; k < 256; ++k) {
            acc = fmaf(wh[(size_t)(k << 10)], h_s[k], acc);
            acc = fmaf(wi[(size_t)(k << 10)], x_s[k], acc);
        }
        g_s[n] = acc;
        __syncthreads();
        if (n < 256) {
            float ig = g_s[n], fg = g_s[n + 256], gg = g_s[n + 512], og = g_s[n + 768];
            float cn = sigf_slow(fg) * c + sigf_slow(ig) * tanhf(gg);
            float hn = sigf_slow(og) * tanhf(cn);
            c = cn; h_s[n] = hn;
        }
        __syncthreads();
        if (n < 160) {
            const int tag = n >> 3, sl = n & 7;
            const float* wrow = wout_s + tag * 257;
            float s = 0.0f;
#pragma unroll 8
            for (int j = 0; j < 32; ++j) { int k = sl + (j << 3); s = fmaf(wrow[k], h_s[k], s); }
            part_s[tag][sl] = s;
        }
        __syncthreads();
        if (n < 20) {
            float s = part_s[n][0];
#pragma unroll
            for (int j = 1; j < 8; ++j) s += part_s[n][j];
            int tp = dir ? (len - 1 - t) : t;
            scout[(size_t)(sbase + tp) * 20 + n] = s;
        }
    }
}

__global__ __launch_bounds__(64) void k_viterbi_fb(
    const int* __restrict__ lens,
    const float* __restrict__ sc_f, const float* __restrict__ sc_b,
    const float* __restrict__ b_out, const float* __restrict__ trans,
    float* __restrict__ out)
{
    const int b = blockIdx.x;
    const int lane = threadIdx.x;
    const int len = lens[b];

    __shared__ float tr_s[20][21];
    __shared__ float fv_s[20];
    __shared__ float term_s[20];
    __shared__ float bo_s[20];
    __shared__ unsigned char bp_s[512][20];
    __shared__ unsigned char path_s[512];

    for (int e = lane; e < 400; e += 64) tr_s[e / 20][e % 20] = trans[e];
    if (lane < 20) { fv_s[lane] = (lane == TAG_START) ? 0.0f : NEGV; bo_s[lane] = b_out[lane]; }
    __syncthreads();

    const size_t sb = (size_t)(b << 9) * 20;
    for (int t = 0; t < len; ++t) {
        float m = 0.0f; int arg = 0;
        if (lane < 20) {
            m = fv_s[0] + tr_s[lane][0]; arg = 0;
#pragma unroll
            for (int k = 1; k < 20; ++k) {
                float v = fv_s[k] + tr_s[lane][k];
                if (v > m) { m = v; arg = k; }
            }
            m += sc_f[sb + t * 20 + lane] + sc_b[sb + t * 20 + lane] + bo_s[lane];
        }
        __syncthreads();
        if (lane < 20) { fv_s[lane] = m; bp_s[t][lane] = (unsigned char)arg; }
        __syncthreads();
    }
    if (lane < 20) term_s[lane] = fv_s[lane] + tr_s[TAG_STOP][lane];
    __syncthreads();
    if (lane == 0) {
        float m = term_s[0]; int arg = 0;
        for (int k = 1; k < 20; ++k) if (term_s[k] > m) { m = term_s[k]; arg = k; }
        out[b] = m;
        int cur = arg;
        path_s[len - 1] = (unsigned char)cur;
        for (int j = len - 1; j >= 1; --j) { cur = bp_s[j][cur]; path_s[j - 1] = (unsigned char)cur; }
    }
    __syncthreads();
    float* po = out + NB + ((size_t)b << 9);
    for (int p = lane; p < NL; p += 64) po[p] = (p < len) ? (float)path_s[p] : 0.0f;
}

// ===========================================================================
extern "C" void kernel_launch(void* const* d_in, const int* in_sizes, int n_in,
                              void* d_out, int out_size, void* d_ws, size_t ws_size,
                              hipStream_t stream)
{
    const int*   sent   = (const int*)d_in[0];
    const int*   lens   = (const int*)d_in[1];
    const float* emb    = (const float*)d_in[2];
    const float* w_ih_f = (const float*)d_in[3];
    const float* w_hh_f = (const float*)d_in[4];
    const float* b_ih_f = (const float*)d_in[5];
    const float* b_hh_f = (const float*)d_in[6];
    const float* w_ih_b = (const float*)d_in[7];
    const float* w_hh_b = (const float*)d_in[8];
    const float* b_ih_b = (const float*)d_in[9];
    const float* b_hh_b = (const float*)d_in[10];
    const float* w_out  = (const float*)d_in[11];
    const float* b_out  = (const float*)d_in[12];
    const float* trans  = (const float*)d_in[13];
    float* out = (float*)d_out;

    char* w = (char*)d_ws;
    const size_t base = 38477824;   // weights(2MB) + bias + state + scores + hout
    int CH = 0;
    const int chs[5] = {512, 256, 128, 64, 32};
    for (int i = 0; i < 5; ++i)
        if (base + (size_t)chs[i] * 524288 <= ws_size) { CH = chs[i]; break; }

    if (CH) {
        // ---- fast path ----
        ushortT* whh16 = (ushortT*)(w);
        ushortT* wih16 = (ushortT*)(w + 1048576);
        float*   biasc = (float*)(w + 2097152);
        ushortT* st_h  = (ushortT*)(w + 2105344);
        float*   st_c  = (float*)(w + 2170880);
        float*   scores= (float*)(w + 2301952);
        ushortT* hout  = (ushortT*)(w + 4923392);
        float*   gin   = (float*)(w + 38477824);

        k_cvtw<<<dim3(1024, 4), 256, 0, stream>>>(w_hh_f, w_hh_b, w_ih_f, w_ih_b, whh16, wih16);
        k_bias<<<2, 1024, 0, stream>>>(b_ih_f, b_hh_f, b_ih_b, b_hh_b, biasc);

        for (int cs = 0; cs < NL; cs += CH) {
            k_gin_mfma<<<dim3(4, CH / 16, 2), 512, 0, stream>>>(
                sent, lens, emb, wih16, biasc, gin, cs, CH);
            k_rec_mfma<<<dim3(4, 2), 512, 0, stream>>>(
                lens, whh16, gin, hout, st_h, st_c, cs, CH);
        }
        k_scores_bf<<<dim3(16, 64), 256, 0, stream>>>(lens, hout, w_out, b_out, scores);
        k_viterbi_s<<<64, 64, 0, stream>>>(lens, scores, trans, out);
    } else {
        // ---- fallback (round-2 proven) ----
        float* ws2   = (float*)d_ws;
        float* thh_f = ws2;
        float* thh_b = thh_f + 262144;
        float* tih_f = thh_b + 262144;
        float* tih_b = tih_f + 262144;
        float* sc_f  = tih_b + 262144;
        float* sc_b  = sc_f + (size_t)NB * NL * NT;

        k_transpose_fb<<<dim3(1024, 4), 256, 0, stream>>>(
            w_hh_f, w_hh_b, w_ih_f, w_ih_b, thh_f, thh_b, tih_f, tih_b);
        k_rec_fb<<<dim3(NB, 2), 1024, 0, stream>>>(
            sent, lens, emb, thh_f, thh_b, tih_f, tih_b,
            b_ih_f, b_hh_f, b_ih_b, b_hh_b, w_out, sc_f, sc_b);
        k_viterbi_fb<<<NB, 64, 0, stream>>>(lens, sc_f, sc_b, b_out, trans, out);
    }
}

// Round 4
// 5413.913 us; speedup vs baseline: 1.8183x; 1.0791x over previous
//
#include <hip/hip_runtime.h>
#include <hip/hip_bf16.h>
#include <math.h>

#define NV 50000
#define NE 256
#define NH 256
#define NT 20
#define NB 64
#define NL 512
#define TAG_START 18
#define TAG_STOP 19
#define NEGV -10000.0f

typedef unsigned short ushortT;
typedef __attribute__((ext_vector_type(4))) float f32x4;
typedef __attribute__((ext_vector_type(8))) short short8;

__device__ __forceinline__ float sigf_slow(float x) { return 1.0f / (1.0f + expf(-x)); }
__device__ __forceinline__ float fsig(float x) { return 1.0f / (1.0f + __expf(-x)); }
__device__ __forceinline__ float ftanh(float x) { return 1.0f - 2.0f / (1.0f + __expf(2.0f * x)); }
__device__ __forceinline__ ushortT f2bf(float f) {
    unsigned int u = __float_as_uint(f);
    u += 0x7fffu + ((u >> 16) & 1u);
    return (ushortT)(u >> 16);
}
__device__ __forceinline__ float bf2f(unsigned int bits16) {
    return __uint_as_float(bits16 << 16);
}

__device__ __forceinline__ void mfma8(const short8 af, const short8* B, f32x4* acc) {
#pragma unroll
    for (int nt = 0; nt < 8; ++nt)
        acc[nt] = __builtin_amdgcn_mfma_f32_16x16x32_bf16(af, B[nt], acc[nt], 0, 0, 0);
}
__device__ __forceinline__ void refill8(short8* B, const ushortT* const* bp, int kt) {
#pragma unroll
    for (int nt = 0; nt < 8; ++nt)
        B[nt] = *(const short8*)(bp[nt] + kt * 32);
}

// ===========================================================================
// FAST PATH
// ===========================================================================

__global__ __launch_bounds__(256) void k_cvtw(
    const float* __restrict__ whh_f, const float* __restrict__ whh_b,
    const float* __restrict__ wih_f, const float* __restrict__ wih_b,
    ushortT* __restrict__ whh16, ushortT* __restrict__ wih16)
{
    int idx = blockIdx.x * 256 + threadIdx.x;     // < 262144
    const float* s; ushortT* d;
    switch (blockIdx.y) {
        case 0: s = whh_f; d = whh16;            break;
        case 1: s = whh_b; d = whh16 + 262144;   break;
        case 2: s = wih_f; d = wih16;            break;
        default: s = wih_b; d = wih16 + 262144;  break;
    }
    d[idx] = f2bf(s[idx]);
}

__global__ __launch_bounds__(1024) void k_bias(
    const float* __restrict__ bih_f, const float* __restrict__ bhh_f,
    const float* __restrict__ bih_b, const float* __restrict__ bhh_b,
    float* __restrict__ biasc)
{
    int n = threadIdx.x;
    if (blockIdx.x == 0) biasc[n] = bih_f[n] + bhh_f[n];
    else                 biasc[1024 + n] = bih_b[n] + bhh_b[n];
}

// K-gin: gin[dir][group][tt][frag-layout] = x_t @ Wih^T + bias  (bf16 MFMA)
__global__ __launch_bounds__(512, 1) void k_gin_mfma(
    const int* __restrict__ sent, const int* __restrict__ lens,
    const float* __restrict__ emb, const ushortT* __restrict__ wih16,
    const float* __restrict__ biasc, float* __restrict__ gin,
    int chunk_start, int CH)
{
    const int g = blockIdx.x, tsub = blockIdx.y, dir = blockIdx.z;
    const int gmax = lens[g * 16];
    const int tt0 = tsub * 16;
    if (chunk_start + tt0 >= gmax) return;

    const int tid = threadIdx.x;
    const int w = tid >> 6, l = tid & 63, lr = l & 15, lg = l >> 4;

    __shared__ char x_raw[16 * 512];

    // B fragments (Wih^T), reused for 16 timesteps (may be partially demoted)
    short8 bfr[8][8];
    float bias_l[8];
    const ushortT* wsrc = wih16 + dir * 262144;
#pragma unroll
    for (int nt = 0; nt < 8; ++nt) {
        int col = (nt >> 1) * 256 + w * 32 + (nt & 1) * 16 + lr;
        bias_l[nt] = biasc[dir * 1024 + col];
#pragma unroll
        for (int kt = 0; kt < 8; ++kt)
            bfr[nt][kt] = *(const short8*)(wsrc + col * 256 + kt * 32 + lg * 8);
    }

    const int srow = tid >> 5, sseg = tid & 31;
    const int slen = lens[g * 16 + srow];
    const int sb = (g * 16 + srow) * 512;

    for (int i = 0; i < 16; ++i) {
        int tg = chunk_start + tt0 + i;
        if (tg >= gmax) break;

        int tsrc = dir ? (slen - 1 - tg) : tg;
        if (tsrc < 0) tsrc = 0;
        if (tsrc > 511) tsrc = 511;
        int tok = sent[sb + tsrc];
        const float* es = emb + (size_t)tok * 256 + sseg * 8;
        float4 e0 = *(const float4*)es;
        float4 e1 = *(const float4*)(es + 4);
        short8 xv;
        xv[0] = (short)f2bf(e0.x); xv[1] = (short)f2bf(e0.y);
        xv[2] = (short)f2bf(e0.z); xv[3] = (short)f2bf(e0.w);
        xv[4] = (short)f2bf(e1.x); xv[5] = (short)f2bf(e1.y);
        xv[6] = (short)f2bf(e1.z); xv[7] = (short)f2bf(e1.w);
        int sa = (srow * 512 + sseg * 16) ^ ((srow & 7) << 4);
        *(short8*)&x_raw[sa] = xv;
        __syncthreads();

        short8 af[8];
#pragma unroll
        for (int kt = 0; kt < 8; ++kt) {
            int a = (lr * 512 + kt * 64 + lg * 16) ^ ((lr & 7) << 4);
            af[kt] = *(const short8*)&x_raw[a];
        }
        f32x4 acc[8];
#pragma unroll
        for (int nt = 0; nt < 8; ++nt) {
            acc[nt][0] = bias_l[nt]; acc[nt][1] = bias_l[nt];
            acc[nt][2] = bias_l[nt]; acc[nt][3] = bias_l[nt];
        }
#pragma unroll
        for (int nt = 0; nt < 8; ++nt)
#pragma unroll
            for (int kt = 0; kt < 8; ++kt)
                acc[nt] = __builtin_amdgcn_mfma_f32_16x16x32_bf16(af[kt], bfr[nt][kt], acc[nt], 0, 0, 0);

        float* ginp = gin + ((size_t)((dir * 4 + g) * CH + (tt0 + i))) * 16384;
#pragma unroll
        for (int nt = 0; nt < 8; ++nt)
            *(f32x4*)(ginp + (w * 8 + nt) * 256 + l * 4) = acc[nt];
        __syncthreads();
    }
}

// K-rec: recurrence with pipelined weight streaming.
//   resident: kt=0,1 (16 frags, 64 VGPR); streamed: kt=2..7 via two 8-frag
//   rotating buffers; gin loaded at step start, consumed in pointwise;
//   h double-buffered in LDS -> one barrier per step.
__global__ __launch_bounds__(512, 2) void k_rec_mfma(
    const int* __restrict__ lens, const ushortT* __restrict__ whh16,
    const float* __restrict__ gin, ushortT* __restrict__ hout,
    ushortT* __restrict__ st_h, float* __restrict__ st_c,
    int chunk_start, int CH)
{
    const int g = blockIdx.x, dir = blockIdx.y;
    const int gmax = lens[g * 16];
    const int nsteps = min(CH, gmax - chunk_start);
    if (nsteps <= 0) return;

    const int tid = threadIdx.x;
    const int w = tid >> 6, l = tid & 63, lr = l & 15, lg = l >> 4;

    __shared__ char h_raw[2][8192];

    int lenr[4];
#pragma unroll
    for (int r = 0; r < 4; ++r) lenr[r] = lens[g * 16 + lg * 4 + r];

    const ushortT* wsrc = whh16 + dir * 262144;

    // per-nt weight base pointers; frag(nt,kt) at bp[nt] + kt*32 elements
    const ushortT* bp[8];
#pragma unroll
    for (int nt = 0; nt < 8; ++nt) {
        int col = (nt >> 1) * 256 + w * 32 + (nt & 1) * 16 + lr;
        bp[nt] = wsrc + (size_t)col * 256 + lg * 8;
    }

    // resident fragments kt = 0,1
    short8 wres0[8], wres1[8];
    refill8(wres0, bp, 0);
    refill8(wres1, bp, 1);

    // state init / restore
    float c[2][4];
    if (chunk_start == 0) {
#pragma unroll
        for (int ut = 0; ut < 2; ++ut)
#pragma unroll
            for (int r = 0; r < 4; ++r) c[ut][r] = 0.0f;
        for (int i = tid; i < 2048; i += 512) ((int*)h_raw[0])[i] = 0;
    } else {
        const float* cs = st_c + ((size_t)((dir * 4 + g) * 512 + tid)) * 8;
#pragma unroll
        for (int ut = 0; ut < 2; ++ut)
#pragma unroll
            for (int r = 0; r < 4; ++r) c[ut][r] = cs[ut * 4 + r];
        const int* hs = (const int*)(st_h + (dir * 4 + g) * 4096);
        for (int i = tid; i < 2048; i += 512) ((int*)h_raw[0])[i] = hs[i];
    }
    __syncthreads();

    const float* ginp = gin + ((size_t)((dir * 4 + g) * CH)) * 16384 + (w * 8) * 256 + l * 4;

    int p = 0;
    for (int tt = 0; tt < nsteps; ++tt) {
        const int t_glob = chunk_start + tt;
        const char* hb = h_raw[p];

        // gin loads: issued now, consumed in pointwise (latency hidden)
        f32x4 gv[8];
        {
            const float* gp = ginp + (size_t)tt * 16384;
#pragma unroll
            for (int nt = 0; nt < 8; ++nt)
                gv[nt] = *(const f32x4*)(gp + nt * 256);
        }

        // stream buffers: issue kt=2,3 immediately
        short8 bufA[8], bufB[8];
        refill8(bufA, bp, 2);
        refill8(bufB, bp, 3);

        f32x4 acc[8];
#pragma unroll
        for (int nt = 0; nt < 8; ++nt) { acc[nt][0] = 0.f; acc[nt][1] = 0.f; acc[nt][2] = 0.f; acc[nt][3] = 0.f; }

        short8 af;
#define LD_AF(kt) { int a_ = (lr * 512 + (kt) * 64 + lg * 16) ^ ((lr & 7) << 4); af = *(const short8*)&hb[a_]; }

        LD_AF(0); mfma8(af, wres0, acc);
        LD_AF(1); mfma8(af, wres1, acc);
        LD_AF(2); mfma8(af, bufA, acc); refill8(bufA, bp, 4);
        LD_AF(3); mfma8(af, bufB, acc); refill8(bufB, bp, 5);
        LD_AF(4); mfma8(af, bufA, acc); refill8(bufA, bp, 6);
        LD_AF(5); mfma8(af, bufB, acc); refill8(bufB, bp, 7);
        LD_AF(6); mfma8(af, bufA, acc);
        LD_AF(7); mfma8(af, bufB, acc);
#undef LD_AF

        // pointwise LSTM cell in registers; h -> other LDS buffer
        char* hw = h_raw[p ^ 1];
#pragma unroll
        for (int ut = 0; ut < 2; ++ut) {
            const int unit = w * 32 + ut * 16 + lr;
#pragma unroll
            for (int r = 0; r < 4; ++r) {
                float i_ = acc[0 + ut][r] + gv[0 + ut][r];
                float f_ = acc[2 + ut][r] + gv[2 + ut][r];
                float g_ = acc[4 + ut][r] + gv[4 + ut][r];
                float o_ = acc[6 + ut][r] + gv[6 + ut][r];
                float cn = fsig(f_) * c[ut][r] + fsig(i_) * ftanh(g_);
                float hn = fsig(o_) * ftanh(cn);
                c[ut][r] = cn;
                ushortT hb16 = f2bf(hn);
                const int row = lg * 4 + r;
                int a_ = (row * 512 + unit * 2) ^ ((row & 7) << 4);
                *(ushortT*)&hw[a_] = hb16;
                if (t_glob < lenr[r]) {
                    int tp = dir ? (lenr[r] - 1 - t_glob) : t_glob;
                    int brow = g * 16 + row;
                    hout[((size_t)(brow * 512 + tp)) * 512 + dir * 256 + unit] = hb16;
                }
            }
        }
        p ^= 1;
        __syncthreads();
    }

    // save state
    float* cs = st_c + ((size_t)((dir * 4 + g) * 512 + tid)) * 8;
#pragma unroll
    for (int ut = 0; ut < 2; ++ut)
#pragma unroll
        for (int r = 0; r < 4; ++r) cs[ut * 4 + r] = c[ut][r];
    int* hs = (int*)(st_h + (dir * 4 + g) * 4096);
    for (int i = tid; i < 2048; i += 512) hs[i] = ((int*)h_raw[p])[i];
}

// K-scores: scores[b,t,:] = h[b,t,:] (bf16) @ w_out^T + b_out  (t < len)
__global__ __launch_bounds__(256) void k_scores_bf(
    const int* __restrict__ lens, const ushortT* __restrict__ hout,
    const float* __restrict__ w_out, const float* __restrict__ b_out,
    float* __restrict__ scores)
{
    const int b = blockIdx.y;
    const int t0 = blockIdx.x * 32;
    const int len = lens[b];
    if (t0 >= len) return;

    __shared__ float w_s[20 * 513];
    __shared__ float row_s[512];
    __shared__ float part_s[20][9];
    __shared__ float bo_s[20];

    const int tid = threadIdx.x;
    for (int e = tid; e < 20 * 512; e += 256) w_s[(e >> 9) * 513 + (e & 511)] = w_out[e];
    if (tid < 20) bo_s[tid] = b_out[tid];
    __syncthreads();

    const int tend = min(t0 + 32, len);
    const int tag = tid >> 3, sl = tid & 7;
    for (int t = t0; t < tend; ++t) {
        const ushortT* hr = hout + ((size_t)(b * 512 + t)) * 512;
        unsigned int v = ((const unsigned int*)hr)[tid];
        row_s[tid * 2] = bf2f(v & 0xffffu);
        row_s[tid * 2 + 1] = bf2f(v >> 16);
        __syncthreads();
        if (tid < 160) {
            float s = 0.0f;
#pragma unroll 8
            for (int j = 0; j < 64; ++j) {
                int k = sl + (((j + tag) & 63) << 3);
                s = fmaf(w_s[tag * 513 + k], row_s[k], s);
            }
            part_s[tag][sl] = s;
        }
        __syncthreads();
        if (tid < 20) {
            float s = bo_s[tid];
#pragma unroll
            for (int j = 0; j < 8; ++j) s += part_s[tid][j];
            scores[((size_t)(b * 512 + t)) * 20 + tid] = s;
        }
        __syncthreads();
    }
}

__global__ __launch_bounds__(64) void k_viterbi_s(
    const int* __restrict__ lens, const float* __restrict__ scores,
    const float* __restrict__ trans, float* __restrict__ out)
{
    const int b = blockIdx.x;
    const int lane = threadIdx.x;
    const int len = lens[b];

    __shared__ float tr_s[20][21];
    __shared__ float fv_s[20];
    __shared__ float term_s[20];
    __shared__ unsigned char bp_s[512][20];
    __shared__ unsigned char path_s[512];

    for (int e = lane; e < 400; e += 64) tr_s[e / 20][e % 20] = trans[e];
    if (lane < 20) fv_s[lane] = (lane == TAG_START) ? 0.0f : NEGV;
    __syncthreads();

    const float* sc = scores + ((size_t)(b << 9)) * 20;
    for (int t = 0; t < len; ++t) {
        float m = 0.0f; int arg = 0;
        if (lane < 20) {
            m = fv_s[0] + tr_s[lane][0]; arg = 0;
#pragma unroll
            for (int k = 1; k < 20; ++k) {
                float v = fv_s[k] + tr_s[lane][k];
                if (v > m) { m = v; arg = k; }
            }
            m += sc[t * 20 + lane];
        }
        __syncthreads();
        if (lane < 20) { fv_s[lane] = m; bp_s[t][lane] = (unsigned char)arg; }
        __syncthreads();
    }

    if (lane < 20) term_s[lane] = fv_s[lane] + tr_s[TAG_STOP][lane];
    __syncthreads();

    if (lane == 0) {
        float m = term_s[0]; int arg = 0;
        for (int k = 1; k < 20; ++k) if (term_s[k] > m) { m = term_s[k]; arg = k; }
        out[b] = m;
        int cur = arg;
        path_s[len - 1] = (unsigned char)cur;
        for (int j = len - 1; j >= 1; --j) {
            cur = bp_s[j][cur];
            path_s[j - 1] = (unsigned char)cur;
        }
    }
    __syncthreads();

    float* po = out + NB + ((size_t)b << 9);
    for (int p = lane; p < NL; p += 64) po[p] = (p < len) ? (float)path_s[p] : 0.0f;
}

// ===========================================================================
// FALLBACK PATH (round-2 proven)
// ===========================================================================
__global__ __launch_bounds__(256) void k_transpose_fb(
    const float* __restrict__ whh_f, const float* __restrict__ whh_b,
    const float* __restrict__ wih_f, const float* __restrict__ wih_b,
    float* __restrict__ thh_f, float* __restrict__ thh_b,
    float* __restrict__ tih_f, float* __restrict__ tih_b)
{
    int e = blockIdx.x * 256 + threadIdx.x;
    const float* wm; float* wt;
    switch (blockIdx.y) {
        case 0: wm = whh_f; wt = thh_f; break;
        case 1: wm = whh_b; wt = thh_b; break;
        case 2: wm = wih_f; wt = tih_f; break;
        default: wm = wih_b; wt = tih_b; break;
    }
    int n = e >> 8, k = e & 255;
    wt[k * 1024 + n] = wm[e];
}

__global__ __launch_bounds__(1024) void k_rec_fb(
    const int* __restrict__ sent, const int* __restrict__ lens,
    const float* __restrict__ emb,
    const float* __restrict__ thh_f, const float* __restrict__ thh_b,
    const float* __restrict__ tih_f, const float* __restrict__ tih_b,
    const float* __restrict__ b_ih_f, const float* __restrict__ b_hh_f,
    const float* __restrict__ b_ih_b, const float* __restrict__ b_hh_b,
    const float* __restrict__ w_out,
    float* __restrict__ sc_f, float* __restrict__ sc_b)
{
    const int b = blockIdx.x, dir = blockIdx.y;
    const int len = lens[b];
    const int n = threadIdx.x;
    const float* Whh = dir ? thh_b : thh_f;
    const float* Wih = dir ? tih_b : tih_f;
    const float* bi = dir ? b_ih_b : b_ih_f;
    const float* bh = dir ? b_hh_b : b_hh_f;
    float* scout = dir ? sc_b : sc_f;

    __shared__ float x_s[256];
    __shared__ float h_s[256];
    __shared__ float g_s[1024];
    __shared__ float bias_s[1024];
    __shared__ float wout_s[20 * 257];
    __shared__ float part_s[20][8];

    bias_s[n] = bi[n] + bh[n];
    for (int e = n; e < 20 * 256; e += 1024)
        wout_s[(e >> 8) * 257 + (e & 255)] = w_out[(e >> 8) * 512 + dir * 256 + (e & 255)];
    if (n < 256) h_s[n] = 0.0f;
    float c = 0.0f;
    __syncthreads();

    const int sbase = b << 9;
    for (int t = 0; t < len; ++t) {
        if (n < 256) {
            int ti = dir ? (len - 1 - t) : t;
            int tok = sent[sbase + ti];
            x_s[n] = emb[(size_t)tok * NE + n];
        }
        __syncthreads();
        float acc = bias_s[n];
        const float* wi = Wih + n;
        const float* wh = Whh + n;
#pragma unroll 8
        for (int k = 0; k < 256; ++k) {
            acc = fmaf(wh[(size_t)(k << 10)], h_s[k], acc);
            acc = fmaf(wi[(size_t)(k << 10)], x_s[k], acc);
        }
        g_s[n] = acc;
        __syncthreads();
        if (n < 256) {
            float ig = g_s[n], fg = g_s[n + 256], gg = g_s[n + 512], og = g_s[n + 768];
            float cn = sigf_slow(fg) * c + sigf_slow(ig) * tanhf(gg);
            float hn = sigf_slow(og) * tanhf(cn);
            c = cn; h_s[n] = hn;
        }
        __syncthreads();
        if (n < 160) {
            const int tag = n >> 3, sl = n & 7;
            const float* wrow = wout_s + tag * 257;
            float s = 0.0f;
#pragma unroll 8
            for (int j = 0; j < 32; ++j) { int k = sl + (j << 3); s = fmaf(wrow[k], h_s[k], s); }
            part_s[tag][sl] = s;
        }
        __syncthreads();
        if (n < 20) {
            float s = part_s[n][0];
#pragma unroll
            for (int j = 1; j < 8; ++j) s += part_s[n][j];
            int tp = dir ? (len - 1 - t) : t;
            scout[(size_t)(sbase + tp) * 20 + n] = s;
        }
    }
}

__global__ __launch_bounds__(64) void k_viterbi_fb(
    const int* __restrict__ lens,
    const float* __restrict__ sc_f, const float* __restrict__ sc_b,
    const float* __restrict__ b_out, const float* __restrict__ trans,
    float* __restrict__ out)
{
    const int b = blockIdx.x;
    const int lane = threadIdx.x;
    const int len = lens[b];

    __shared__ float tr_s[20][21];
    __shared__ float fv_s[20];
    __shared__ float term_s[20];
    __shared__ float bo_s[20];
    __shared__ unsigned char bp_s[512][20];
    __shared__ unsigned char path_s[512];

    for (int e = lane; e < 400; e += 64) tr_s[e / 20][e % 20] = trans[e];
    if (lane < 20) { fv_s[lane] = (lane == TAG_START) ? 0.0f : NEGV; bo_s[lane] = b_out[lane]; }
    __syncthreads();

    const size_t sb = (size_t)(b << 9) * 20;
    for (int t = 0; t < len; ++t) {
        float m = 0.0f; int arg = 0;
        if (lane < 20) {
            m = fv_s[0] + tr_s[lane][0]; arg = 0;
#pragma unroll
            for (int k = 1; k < 20; ++k) {
                float v = fv_s[k] + tr_s[lane][k];
                if (v > m) { m = v; arg = k; }
            }
            m += sc_f[sb + t * 20 + lane] + sc_b[sb + t * 20 + lane] + bo_s[lane];
        }
        __syncthreads();
        if (lane < 20) { fv_s[lane] = m; bp_s[t][lane] = (unsigned char)arg; }
        __syncthreads();
    }
    if (lane < 20) term_s[lane] = fv_s[lane] + tr_s[TAG_STOP][lane];
    __syncthreads();
    if (lane == 0) {
        float m = term_s[0]; int arg = 0;
        for (int k = 1; k < 20; ++k) if (term_s[k] > m) { m = term_s[k]; arg = k; }
        out[b] = m;
        int cur = arg;
        path_s[len - 1] = (unsigned char)cur;
        for (int j = len - 1; j >= 1; --j) { cur = bp_s[j][cur]; path_s[j - 1] = (unsigned char)cur; }
    }
    __syncthreads();
    float* po = out + NB + ((size_t)b << 9);
    for (int p = lane; p < NL; p += 64) po[p] = (p < len) ? (float)path_s[p] : 0.0f;
}

// ===========================================================================
extern "C" void kernel_launch(void* const* d_in, const int* in_sizes, int n_in,
                              void* d_out, int out_size, void* d_ws, size_t ws_size,
                              hipStream_t stream)
{
    const int*   sent   = (const int*)d_in[0];
    const int*   lens   = (const int*)d_in[1];
    const float* emb    = (const float*)d_in[2];
    const float* w_ih_f = (const float*)d_in[3];
    const float* w_hh_f = (const float*)d_in[4];
    const float* b_ih_f = (const float*)d_in[5];
    const float* b_hh_f = (const float*)d_in[6];
    const float* w_ih_b = (const float*)d_in[7];
    const float* w_hh_b = (const float*)d_in[8];
    const float* b_ih_b = (const float*)d_in[9];
    const float* b_hh_b = (const float*)d_in[10];
    const float* w_out  = (const float*)d_in[11];
    const float* b_out  = (const float*)d_in[12];
    const float* trans  = (const float*)d_in[13];
    float* out = (float*)d_out;

    char* w = (char*)d_ws;
    const size_t base = 38477824;
    int CH = 0;
    const int chs[5] = {512, 256, 128, 64, 32};
    for (int i = 0; i < 5; ++i)
        if (base + (size_t)chs[i] * 524288 <= ws_size) { CH = chs[i]; break; }

    if (CH) {
        ushortT* whh16 = (ushortT*)(w);
        ushortT* wih16 = (ushortT*)(w + 1048576);
        float*   biasc = (float*)(w + 2097152);
        ushortT* st_h  = (ushortT*)(w + 2105344);
        float*   st_c  = (float*)(w + 2170880);
        float*   scores= (float*)(w + 2301952);
        ushortT* hout  = (ushortT*)(w + 4923392);
        float*   gin   = (float*)(w + 38477824);

        k_cvtw<<<dim3(1024, 4), 256, 0, stream>>>(w_hh_f, w_hh_b, w_ih_f, w_ih_b, whh16, wih16);
        k_bias<<<2, 1024, 0, stream>>>(b_ih_f, b_hh_f, b_ih_b, b_hh_b, biasc);

        for (int cs = 0; cs < NL; cs += CH) {
            k_gin_mfma<<<dim3(4, CH / 16, 2), 512, 0, stream>>>(
                sent, lens, emb, wih16, biasc, gin, cs, CH);
            k_rec_mfma<<<dim3(4, 2), 512, 0, stream>>>(
                lens, whh16, gin, hout, st_h, st_c, cs, CH);
        }
        k_scores_bf<<<dim3(16, 64), 256, 0, stream>>>(lens, hout, w_out, b_out, scores);
        k_viterbi_s<<<64, 64, 0, stream>>>(lens, scores, trans, out);
    } else {
        float* ws2   = (float*)d_ws;
        float* thh_f = ws2;
        float* thh_b = thh_f + 262144;
        float* tih_f = thh_b + 262144;
        float* tih_b = tih_f + 262144;
        float* sc_f  = tih_b + 262144;
        float* sc_b  = sc_f + (size_t)NB * NL * NT;

        k_transpose_fb<<<dim3(1024, 4), 256, 0, stream>>>(
            w_hh_f, w_hh_b, w_ih_f, w_ih_b, thh_f, thh_b, tih_f, tih_b);
        k_rec_fb<<<dim3(NB, 2), 1024, 0, stream>>>(
            sent, lens, emb, thh_f, thh_b, tih_f, tih_b,
            b_ih_f, b_hh_f, b_ih_b, b_hh_b, w_out, sc_f, sc_b);
        k_viterbi_fb<<<NB, 64, 0, stream>>>(lens, sc_f, sc_b, b_out, trans, out);
    }
}

// Round 5
// 2478.006 us; speedup vs baseline: 3.9726x; 2.1848x over previous
//
#include <hip/hip_runtime.h>
#include <hip/hip_bf16.h>
#include <math.h>

#define NV 50000
#define NE 256
#define NH 256
#define NT 20
#define NB 64
#define NL 512
#define TAG_START 18
#define TAG_STOP 19
#define NEGV -10000.0f

typedef unsigned short ushortT;
typedef __attribute__((ext_vector_type(4))) float f32x4;
typedef __attribute__((ext_vector_type(8))) short short8;

__device__ __forceinline__ float sigf_slow(float x) { return 1.0f / (1.0f + expf(-x)); }
__device__ __forceinline__ float fsig(float x) { return 1.0f / (1.0f + __expf(-x)); }
__device__ __forceinline__ float ftanh(float x) { return 1.0f - 2.0f / (1.0f + __expf(2.0f * x)); }
__device__ __forceinline__ ushortT f2bf(float f) {
    unsigned int u = __float_as_uint(f);
    u += 0x7fffu + ((u >> 16) & 1u);
    return (ushortT)(u >> 16);
}
__device__ __forceinline__ float bf2f(unsigned int bits16) {
    return __uint_as_float(bits16 << 16);
}

// ===========================================================================
// FAST PATH
// ===========================================================================

__global__ __launch_bounds__(256) void k_cvtw(
    const float* __restrict__ whh_f, const float* __restrict__ whh_b,
    const float* __restrict__ wih_f, const float* __restrict__ wih_b,
    ushortT* __restrict__ whh16, ushortT* __restrict__ wih16)
{
    int idx = blockIdx.x * 256 + threadIdx.x;     // < 262144
    const float* s; ushortT* d;
    switch (blockIdx.y) {
        case 0: s = whh_f; d = whh16;            break;
        case 1: s = whh_b; d = whh16 + 262144;   break;
        case 2: s = wih_f; d = wih16;            break;
        default: s = wih_b; d = wih16 + 262144;  break;
    }
    d[idx] = f2bf(s[idx]);
}

__global__ __launch_bounds__(1024) void k_bias(
    const float* __restrict__ bih_f, const float* __restrict__ bhh_f,
    const float* __restrict__ bih_b, const float* __restrict__ bhh_b,
    float* __restrict__ biasc)
{
    int n = threadIdx.x;
    if (blockIdx.x == 0) biasc[n] = bih_f[n] + bhh_f[n];
    else                 biasc[1024 + n] = bih_b[n] + bhh_b[n];
}

// K-gin: canonical layout gin[dirg][t][col*16 + row] = x_t @ Wih^T + bias
__global__ __launch_bounds__(512, 1) void k_gin_mfma(
    const int* __restrict__ sent, const int* __restrict__ lens,
    const float* __restrict__ emb, const ushortT* __restrict__ wih16,
    const float* __restrict__ biasc, float* __restrict__ gin,
    int chunk_start, int CH)
{
    const int g = blockIdx.x, tsub = blockIdx.y, dir = blockIdx.z;
    const int gmax = lens[g * 16];
    const int tt0 = tsub * 16;
    if (chunk_start + tt0 >= gmax) return;

    const int tid = threadIdx.x;
    const int w = tid >> 6, l = tid & 63, lr = l & 15, lg = l >> 4;

    __shared__ char x_raw[16 * 512];

    short8 bfr[8][8];
    float bias_l[8];
    const ushortT* wsrc = wih16 + dir * 262144;
#pragma unroll
    for (int nt = 0; nt < 8; ++nt) {
        int col = (nt >> 1) * 256 + w * 32 + (nt & 1) * 16 + lr;
        bias_l[nt] = biasc[dir * 1024 + col];
#pragma unroll
        for (int kt = 0; kt < 8; ++kt)
            bfr[nt][kt] = *(const short8*)(wsrc + col * 256 + kt * 32 + lg * 8);
    }

    const int srow = tid >> 5, sseg = tid & 31;
    const int slen = lens[g * 16 + srow];
    const int sb = (g * 16 + srow) * 512;

    for (int i = 0; i < 16; ++i) {
        int tg = chunk_start + tt0 + i;
        if (tg >= gmax) break;

        int tsrc = dir ? (slen - 1 - tg) : tg;
        if (tsrc < 0) tsrc = 0;
        if (tsrc > 511) tsrc = 511;
        int tok = sent[sb + tsrc];
        const float* es = emb + (size_t)tok * 256 + sseg * 8;
        float4 e0 = *(const float4*)es;
        float4 e1 = *(const float4*)(es + 4);
        short8 xv;
        xv[0] = (short)f2bf(e0.x); xv[1] = (short)f2bf(e0.y);
        xv[2] = (short)f2bf(e0.z); xv[3] = (short)f2bf(e0.w);
        xv[4] = (short)f2bf(e1.x); xv[5] = (short)f2bf(e1.y);
        xv[6] = (short)f2bf(e1.z); xv[7] = (short)f2bf(e1.w);
        int sa = (srow * 512 + sseg * 16) ^ ((srow & 7) << 4);
        *(short8*)&x_raw[sa] = xv;
        __syncthreads();

        short8 af[8];
#pragma unroll
        for (int kt = 0; kt < 8; ++kt) {
            int a = (lr * 512 + kt * 64 + lg * 16) ^ ((lr & 7) << 4);
            af[kt] = *(const short8*)&x_raw[a];
        }
        f32x4 acc[8];
#pragma unroll
        for (int nt = 0; nt < 8; ++nt) {
            acc[nt][0] = bias_l[nt]; acc[nt][1] = bias_l[nt];
            acc[nt][2] = bias_l[nt]; acc[nt][3] = bias_l[nt];
        }
#pragma unroll
        for (int nt = 0; nt < 8; ++nt)
#pragma unroll
            for (int kt = 0; kt < 8; ++kt)
                acc[nt] = __builtin_amdgcn_mfma_f32_16x16x32_bf16(af[kt], bfr[nt][kt], acc[nt], 0, 0, 0);

        float* ginp = gin + ((size_t)((dir * 4 + g) * CH + (tt0 + i))) * 16384;
#pragma unroll
        for (int nt = 0; nt < 8; ++nt) {
            int col_g = (nt >> 1) * 256 + w * 32 + (nt & 1) * 16 + lr;
            *(f32x4*)(ginp + col_g * 16 + lg * 4) = acc[nt];
        }
        __syncthreads();
    }
}

// K-rec: weights fully VGPR-resident across 2 CUs per (group,dir).
//   WG = (g, dir, half). half owns units [half*128, half*128+128), all 4 gates.
//   Per step the halves exchange h-halves via an LLC mailbox (agent-scope
//   atomics + monotonic flags).
__global__
__attribute__((amdgpu_flat_work_group_size(512, 512)))
__attribute__((amdgpu_waves_per_eu(2, 2)))
void k_rec_mfma(
    const int* __restrict__ lens, const ushortT* __restrict__ whh16,
    const float* __restrict__ gin, ushortT* __restrict__ hout,
    ushortT* __restrict__ st_h, float* __restrict__ st_c,
    ushortT* __restrict__ hex, unsigned int* __restrict__ flags,
    int chunk_start, int CH)
{
    const int g = blockIdx.x, dir = blockIdx.y, half = blockIdx.z;
    const int gmax = lens[g * 16];
    const int nsteps = min(CH, gmax - chunk_start);
    if (nsteps <= 0) return;

    const int tid = threadIdx.x;
    const int w = tid >> 6, l = tid & 63, lr = l & 15, lg = l >> 4;

    __shared__ char h_s[2][8192];   // [buf][row*512B + unit*2B], XOR-swizzled

    int lenr[4];
#pragma unroll
    for (int r = 0; r < 4; ++r) lenr[r] = lens[g * 16 + lg * 4 + r];

    // resident weights: 4 gates x 8 k-tiles for this lane's unit
    const int ucol = half * 128 + w * 16 + lr;          // unit owned by lane
    short8 bfr[4][8];
    {
        const ushortT* wsrc = whh16 + dir * 262144;
#pragma unroll
        for (int nt = 0; nt < 4; ++nt) {
            const ushortT* wp = wsrc + (size_t)(nt * 256 + ucol) * 256 + lg * 8;
#pragma unroll
            for (int kt = 0; kt < 8; ++kt)
                bfr[nt][kt] = *(const short8*)(wp + kt * 32);
        }
    }

    // state init / restore
    float c[4];
    if (chunk_start == 0) {
#pragma unroll
        for (int r = 0; r < 4; ++r) c[r] = 0.0f;
        for (int i = tid; i < 2048; i += 512) ((int*)h_s[0])[i] = 0;
    } else {
        const float* cs = st_c + ((size_t)((dir * 4 + g) * 2 + half)) * 2048 + tid * 4;
#pragma unroll
        for (int r = 0; r < 4; ++r) c[r] = cs[r];
        const int* hs = (const int*)st_h + (dir * 4 + g) * 2048;
        for (int i = tid; i < 2048; i += 512) ((int*)h_s[0])[i] = hs[i];
    }
    __syncthreads();

    // exchange constants
    unsigned int* exu = (unsigned int*)(hex + (dir * 4 + g) * 8192);  // 2 slots x 2048 uints
    unsigned int* flagMe = flags + (dir * 4 + g) * 2 + half;
    unsigned int* flagPeer = flags + (dir * 4 + g) * 2 + (half ^ 1);

    int own_lds[2], own_gid[2], peer_lds[2], peer_gid[2];
#pragma unroll
    for (int s2 = 0; s2 < 2; ++s2) {
        int i = tid * 2 + s2;
        int row = i >> 6, j = i & 63;
        int mu = half * 128 + j * 2;
        own_lds[s2] = (row * 512 + mu * 2) ^ ((row & 7) << 4);
        own_gid[s2] = row * 128 + half * 64 + j;
        int pu = (half ^ 1) * 128 + j * 2;
        peer_lds[s2] = (row * 512 + pu * 2) ^ ((row & 7) << 4);
        peer_gid[s2] = row * 128 + (half ^ 1) * 64 + j;
    }

    const float* ginp = gin + ((size_t)((dir * 4 + g) * CH)) * 16384;
    int p = 0;
    for (int tt = 0; tt < nsteps; ++tt) {
        const int t_glob = chunk_start + tt;

        // gin (input projection) for my 4 gate-cols; consumed in pointwise
        f32x4 gv[4];
#pragma unroll
        for (int nt = 0; nt < 4; ++nt)
            gv[nt] = *(const f32x4*)(ginp + (size_t)tt * 16384 + (nt * 256 + ucol) * 16 + lg * 4);

        // h @ Whh^T on resident weights
        const char* hb = h_s[p];
        f32x4 acc[4];
#pragma unroll
        for (int nt = 0; nt < 4; ++nt) { acc[nt][0] = 0.f; acc[nt][1] = 0.f; acc[nt][2] = 0.f; acc[nt][3] = 0.f; }
#pragma unroll
        for (int kt = 0; kt < 8; ++kt) {
            int a_ = (lr * 512 + kt * 64 + lg * 16) ^ ((lr & 7) << 4);
            short8 af = *(const short8*)&hb[a_];
#pragma unroll
            for (int nt = 0; nt < 4; ++nt)
                acc[nt] = __builtin_amdgcn_mfma_f32_16x16x32_bf16(af, bfr[nt][kt], acc[nt], 0, 0, 0);
        }

        // pointwise cell (lane has all 4 gates of unit ucol, rows lg*4+r)
        char* hw = h_s[p ^ 1];
#pragma unroll
        for (int r = 0; r < 4; ++r) {
            float i_ = acc[0][r] + gv[0][r];
            float f_ = acc[1][r] + gv[1][r];
            float g_ = acc[2][r] + gv[2][r];
            float o_ = acc[3][r] + gv[3][r];
            float cn = fsig(f_) * c[r] + fsig(i_) * ftanh(g_);
            float hn = fsig(o_) * ftanh(cn);
            c[r] = cn;
            ushortT hb16 = f2bf(hn);
            int row = lg * 4 + r;
            int a_ = (row * 512 + ucol * 2) ^ ((row & 7) << 4);
            *(ushortT*)&hw[a_] = hb16;
            if (t_glob < lenr[r]) {
                int tp = dir ? (lenr[r] - 1 - t_glob) : t_glob;
                hout[((size_t)((g * 16 + row) * 512 + tp)) * 512 + dir * 256 + ucol] = hb16;
            }
        }
        __syncthreads();   // own half of h(t+1) complete in LDS

        // publish own half to LLC mailbox
        unsigned int* exs = exu + ((t_glob + 1) & 1) * 2048;
#pragma unroll
        for (int s2 = 0; s2 < 2; ++s2) {
            unsigned int v = *(const unsigned int*)&hw[own_lds[s2]];
            __hip_atomic_store(&exs[own_gid[s2]], v, __ATOMIC_RELAXED, __HIP_MEMORY_SCOPE_AGENT);
        }
        __syncthreads();   // drains vmcnt -> all sc1 stores acked at LLC

        if (tid == 0) {
            __hip_atomic_store(flagMe, (unsigned int)(t_glob + 1), __ATOMIC_RELEASE, __HIP_MEMORY_SCOPE_AGENT);
            int guard = 0;
            while (__hip_atomic_load(flagPeer, __ATOMIC_RELAXED, __HIP_MEMORY_SCOPE_AGENT) < (unsigned int)(t_glob + 1)
                   && ++guard < (1 << 16)) {}
        }
        __syncthreads();

        // fetch peer half into LDS
#pragma unroll
        for (int s2 = 0; s2 < 2; ++s2) {
            unsigned int v = __hip_atomic_load(&exs[peer_gid[s2]], __ATOMIC_RELAXED, __HIP_MEMORY_SCOPE_AGENT);
            *(unsigned int*)&hw[peer_lds[s2]] = v;
        }
        __syncthreads();
        p ^= 1;
    }

    // save state
    float* cs = st_c + ((size_t)((dir * 4 + g) * 2 + half)) * 2048 + tid * 4;
#pragma unroll
    for (int r = 0; r < 4; ++r) cs[r] = c[r];
    if (half == 0) {
        int* hs = (int*)st_h + (dir * 4 + g) * 2048;
        for (int i = tid; i < 2048; i += 512) hs[i] = ((int*)h_s[p])[i];
    }
}

// K-scores: scores[b,t,:] = h[b,t,:] (bf16) @ w_out^T + b_out  (t < len)
__global__ __launch_bounds__(256) void k_scores_bf(
    const int* __restrict__ lens, const ushortT* __restrict__ hout,
    const float* __restrict__ w_out, const float* __restrict__ b_out,
    float* __restrict__ scores)
{
    const int b = blockIdx.y;
    const int t0 = blockIdx.x * 32;
    const int len = lens[b];
    if (t0 >= len) return;

    __shared__ float w_s[20 * 513];
    __shared__ float row_s[512];
    __shared__ float part_s[20][9];
    __shared__ float bo_s[20];

    const int tid = threadIdx.x;
    for (int e = tid; e < 20 * 512; e += 256) w_s[(e >> 9) * 513 + (e & 511)] = w_out[e];
    if (tid < 20) bo_s[tid] = b_out[tid];
    __syncthreads();

    const int tend = min(t0 + 32, len);
    const int tag = tid >> 3, sl = tid & 7;
    for (int t = t0; t < tend; ++t) {
        const ushortT* hr = hout + ((size_t)(b * 512 + t)) * 512;
        unsigned int v = ((const unsigned int*)hr)[tid];
        row_s[tid * 2] = bf2f(v & 0xffffu);
        row_s[tid * 2 + 1] = bf2f(v >> 16);
        __syncthreads();
        if (tid < 160) {
            float s = 0.0f;
#pragma unroll 8
            for (int j = 0; j < 64; ++j) {
                int k = sl + (((j + tag) & 63) << 3);
                s = fmaf(w_s[tag * 513 + k], row_s[k], s);
            }
            part_s[tag][sl] = s;
        }
        __syncthreads();
        if (tid < 20) {
            float s = bo_s[tid];
#pragma unroll
            for (int j = 0; j < 8; ++j) s += part_s[tid][j];
            scores[((size_t)(b * 512 + t)) * 20 + tid] = s;
        }
        __syncthreads();
    }
}

__global__ __launch_bounds__(64) void k_viterbi_s(
    const int* __restrict__ lens, const float* __restrict__ scores,
    const float* __restrict__ trans, float* __restrict__ out)
{
    const int b = blockIdx.x;
    const int lane = threadIdx.x;
    const int len = lens[b];

    __shared__ float tr_s[20][21];
    __shared__ float fv_s[20];
    __shared__ float term_s[20];
    __shared__ unsigned char bp_s[512][20];
    __shared__ unsigned char path_s[512];

    for (int e = lane; e < 400; e += 64) tr_s[e / 20][e % 20] = trans[e];
    if (lane < 20) fv_s[lane] = (lane == TAG_START) ? 0.0f : NEGV;
    __syncthreads();

    const float* sc = scores + ((size_t)(b << 9)) * 20;
    for (int t = 0; t < len; ++t) {
        float m = 0.0f; int arg = 0;
        if (lane < 20) {
            m = fv_s[0] + tr_s[lane][0]; arg = 0;
#pragma unroll
            for (int k = 1; k < 20; ++k) {
                float v = fv_s[k] + tr_s[lane][k];
                if (v > m) { m = v; arg = k; }
            }
            m += sc[t * 20 + lane];
        }
        __syncthreads();
        if (lane < 20) { fv_s[lane] = m; bp_s[t][lane] = (unsigned char)arg; }
        __syncthreads();
    }

    if (lane < 20) term_s[lane] = fv_s[lane] + tr_s[TAG_STOP][lane];
    __syncthreads();

    if (lane == 0) {
        float m = term_s[0]; int arg = 0;
        for (int k = 1; k < 20; ++k) if (term_s[k] > m) { m = term_s[k]; arg = k; }
        out[b] = m;
        int cur = arg;
        path_s[len - 1] = (unsigned char)cur;
        for (int j = len - 1; j >= 1; --j) {
            cur = bp_s[j][cur];
            path_s[j - 1] = (unsigned char)cur;
        }
    }
    __syncthreads();

    float* po = out + NB + ((size_t)b << 9);
    for (int p = lane; p < NL; p += 64) po[p] = (p < len) ? (float)path_s[p] : 0.0f;
}

// ===========================================================================
// FALLBACK PATH (round-2 proven)
// ===========================================================================
__global__ __launch_bounds__(256) void k_transpose_fb(
    const float* __restrict__ whh_f, const float* __restrict__ whh_b,
    const float* __restrict__ wih_f, const float* __restrict__ wih_b,
    float* __restrict__ thh_f, float* __restrict__ thh_b,
    float* __restrict__ tih_f, float* __restrict__ tih_b)
{
    int e = blockIdx.x * 256 + threadIdx.x;
    const float* wm; float* wt;
    switch (blockIdx.y) {
        case 0: wm = whh_f; wt = thh_f; break;
        case 1: wm = whh_b; wt = thh_b; break;
        case 2: wm = wih_f; wt = tih_f; break;
        default: wm = wih_b; wt = tih_b; break;
    }
    int n = e >> 8, k = e & 255;
    wt[k * 1024 + n] = wm[e];
}

__global__ __launch_bounds__(1024) void k_rec_fb(
    const int* __restrict__ sent, const int* __restrict__ lens,
    const float* __restrict__ emb,
    const float* __restrict__ thh_f, const float* __restrict__ thh_b,
    const float* __restrict__ tih_f, const float* __restrict__ tih_b,
    const float* __restrict__ b_ih_f, const float* __restrict__ b_hh_f,
    const float* __restrict__ b_ih_b, const float* __restrict__ b_hh_b,
    const float* __restrict__ w_out,
    float* __restrict__ sc_f, float* __restrict__ sc_b)
{
    const int b = blockIdx.x, dir = blockIdx.y;
    const int len = lens[b];
    const int n = threadIdx.x;
    const float* Whh = dir ? thh_b : thh_f;
    const float* Wih = dir ? tih_b : tih_f;
    const float* bi = dir ? b_ih_b : b_ih_f;
    const float* bh = dir ? b_hh_b : b_hh_f;
    float* scout = dir ? sc_b : sc_f;

    __shared__ float x_s[256];
    __shared__ float h_s[256];
    __shared__ float g_s[1024];
    __shared__ float bias_s[1024];
    __shared__ float wout_s[20 * 257];
    __shared__ float part_s[20][8];

    bias_s[n] = bi[n] + bh[n];
    for (int e = n; e < 20 * 256; e += 1024)
        wout_s[(e >> 8) * 257 + (e & 255)] = w_out[(e >> 8) * 512 + dir * 256 + (e & 255)];
    if (n < 256) h_s[n] = 0.0f;
    float c = 0.0f;
    __syncthreads();

    const int sbase = b << 9;
    for (int t = 0; t < len; ++t) {
        if (n < 256) {
            int ti = dir ? (len - 1 - t) : t;
            int tok = sent[sbase + ti];
            x_s[n] = emb[(size_t)tok * NE + n];
        }
        __syncthreads();
        float acc = bias_s[n];
        const float* wi = Wih + n;
        const float* wh = Whh + n;
#pragma unroll 8
        for (int k = 0; k < 256; ++k) {
            acc = fmaf(wh[(size_t)(k << 10)], h_s[k], acc);
            acc = fmaf(wi[(size_t)(k << 10)], x_s[k], acc);
        }
        g_s[n] = acc;
        __syncthreads();
        if (n < 256) {
            float ig = g_s[n], fg = g_s[n + 256], gg = g_s[n + 512], og = g_s[n + 768];
            float cn = sigf_slow(fg) * c + sigf_slow(ig) * tanhf(gg);
            float hn = sigf_slow(og) * tanhf(cn);
            c = cn; h_s[n] = hn;
        }
        __syncthreads();
        if (n < 160) {
            const int tag = n >> 3, sl = n & 7;
            const float* wrow = wout_s + tag * 257;
            float s = 0.0f;
#pragma unroll 8
            for (int j = 0; j < 32; ++j) { int k = sl + (j << 3); s = fmaf(wrow[k], h_s[k], s); }
            part_s[tag][sl] = s;
        }
        __syncthreads();
        if (n < 20) {
            float s = part_s[n][0];
#pragma unroll
            for (int j = 1; j < 8; ++j) s += part_s[n][j];
            int tp = dir ? (len - 1 - t) : t;
            scout[(size_t)(sbase + tp) * 20 + n] = s;
        }
    }
}

__global__ __launch_bounds__(64) void k_viterbi_fb(
    const int* __restrict__ lens,
    const float* __restrict__ sc_f, const float* __restrict__ sc_b,
    const float* __restrict__ b_out, const float* __restrict__ trans,
    float* __restrict__ out)
{
    const int b = blockIdx.x;
    const int lane = threadIdx.x;
    const int len = lens[b];

    __shared__ float tr_s[20][21];
    __shared__ float fv_s[20];
    __shared__ float term_s[20];
    __shared__ float bo_s[20];
    __shared__ unsigned char bp_s[512][20];
    __shared__ unsigned char path_s[512];

    for (int e = lane; e < 400; e += 64) tr_s[e / 20][e % 20] = trans[e];
    if (lane < 20) { fv_s[lane] = (lane == TAG_START) ? 0.0f : NEGV; bo_s[lane] = b_out[lane]; }
    __syncthreads();

    const size_t sb = (size_t)(b << 9) * 20;
    for (int t = 0; t < len; ++t) {
        float m = 0.0f; int arg = 0;
        if (lane < 20) {
            m = fv_s[0] + tr_s[lane][0]; arg = 0;
#pragma unroll
            for (int k = 1; k < 20; ++k) {
                float v = fv_s[k] + tr_s[lane][k];
                if (v > m) { m = v; arg = k; }
            }
            m += sc_f[sb + t * 20 + lane] + sc_b[sb + t * 20 + lane] + bo_s[lane];
        }
        __syncthreads();
        if (lane < 20) { fv_s[lane] = m; bp_s[t][lane] = (unsigned char)arg; }
        __syncthreads();
    }
    if (lane < 20) term_s[lane] = fv_s[lane] + tr_s[TAG_STOP][lane];
    __syncthreads();
    if (lane == 0) {
        float m = term_s[0]; int arg = 0;
        for (int k = 1; k < 20; ++k) if (term_s[k] > m) { m = term_s[k]; arg = k; }
        out[b] = m;
        int cur = arg;
        path_s[len - 1] = (unsigned char)cur;
        for (int j = len - 1; j >= 1; --j) { cur = bp_s[j][cur]; path_s[j - 1] = (unsigned char)cur; }
    }
    __syncthreads();
    float* po = out + NB + ((size_t)b << 9);
    for (int p = lane; p < NL; p += 64) po[p] = (p < len) ? (float)path_s[p] : 0.0f;
}

// ===========================================================================
extern "C" void kernel_launch(void* const* d_in, const int* in_sizes, int n_in,
                              void* d_out, int out_size, void* d_ws, size_t ws_size,
                              hipStream_t stream)
{
    const int*   sent   = (const int*)d_in[0];
    const int*   lens   = (const int*)d_in[1];
    const float* emb    = (const float*)d_in[2];
    const float* w_ih_f = (const float*)d_in[3];
    const float* w_hh_f = (const float*)d_in[4];
    const float* b_ih_f = (const float*)d_in[5];
    const float* b_hh_f = (const float*)d_in[6];
    const float* w_ih_b = (const float*)d_in[7];
    const float* w_hh_b = (const float*)d_in[8];
    const float* b_ih_b = (const float*)d_in[9];
    const float* b_hh_b = (const float*)d_in[10];
    const float* w_out  = (const float*)d_in[11];
    const float* b_out  = (const float*)d_in[12];
    const float* trans  = (const float*)d_in[13];
    float* out = (float*)d_out;

    char* w = (char*)d_ws;
    // layout:
    //  whh16   @ 0        (1 MB)     wih16 @ 1048576 (1 MB)
    //  biasc   @ 2097152  (8 KB)     st_h  @ 2105344 (64 KB)
    //  st_c    @ 2170880  (128 KB)   hex   @ 2301952 (128 KB)
    //  flags   @ 2433024  (4 KB)     scores@ 2437120 (2.5 MB)
    //  hout    @ 5058560  (32 MB)    gin   @ 38612992 (CH*512 KB)
    const size_t base = 38612992;
    int CH = 0;
    const int chs[6] = {512, 256, 192, 128, 64, 32};
    for (int i = 0; i < 6; ++i)
        if (base + (size_t)chs[i] * 524288 <= ws_size) { CH = chs[i]; break; }

    if (CH) {
        ushortT* whh16 = (ushortT*)(w);
        ushortT* wih16 = (ushortT*)(w + 1048576);
        float*   biasc = (float*)(w + 2097152);
        ushortT* st_h  = (ushortT*)(w + 2105344);
        float*   st_c  = (float*)(w + 2170880);
        ushortT* hex   = (ushortT*)(w + 2301952);
        unsigned int* flags = (unsigned int*)(w + 2433024);
        float*   scores= (float*)(w + 2437120);
        ushortT* hout  = (ushortT*)(w + 5058560);
        float*   gin   = (float*)(w + base);

        hipMemsetAsync(flags, 0, 4096, stream);
        k_cvtw<<<dim3(1024, 4), 256, 0, stream>>>(w_hh_f, w_hh_b, w_ih_f, w_ih_b, whh16, wih16);
        k_bias<<<2, 1024, 0, stream>>>(b_ih_f, b_hh_f, b_ih_b, b_hh_b, biasc);

        for (int cs = 0; cs < NL; cs += CH) {
            k_gin_mfma<<<dim3(4, CH / 16, 2), 512, 0, stream>>>(
                sent, lens, emb, wih16, biasc, gin, cs, CH);
            k_rec_mfma<<<dim3(4, 2, 2), 512, 0, stream>>>(
                lens, whh16, gin, hout, st_h, st_c, hex, flags, cs, CH);
        }
        k_scores_bf<<<dim3(16, 64), 256, 0, stream>>>(lens, hout, w_out, b_out, scores);
        k_viterbi_s<<<64, 64, 0, stream>>>(lens, scores, trans, out);
    } else {
        float* ws2   = (float*)d_ws;
        float* thh_f = ws2;
        float* thh_b = thh_f + 262144;
        float* tih_f = thh_b + 262144;
        float* tih_b = tih_f + 262144;
        float* sc_f  = tih_b + 262144;
        float* sc_b  = sc_f + (size_t)NB * NL * NT;

        k_transpose_fb<<<dim3(1024, 4), 256, 0, stream>>>(
            w_hh_f, w_hh_b, w_ih_f, w_ih_b, thh_f, thh_b, tih_f, tih_b);
        k_rec_fb<<<dim3(NB, 2), 1024, 0, stream>>>(
            sent, lens, emb, thh_f, thh_b, tih_f, tih_b,
            b_ih_f, b_hh_f, b_ih_b, b_hh_b, w_out, sc_f, sc_b);
        k_viterbi_fb<<<NB, 64, 0, stream>>>(lens, sc_f, sc_b, b_out, trans, out);
    }
}

// Round 6
// 2230.062 us; speedup vs baseline: 4.4143x; 1.1112x over previous
//
#include <hip/hip_runtime.h>
#include <hip/hip_bf16.h>
#include <math.h>

#define NV 50000
#define NE 256
#define NH 256
#define NT 20
#define NB 64
#define NL 512
#define TAG_START 18
#define TAG_STOP 19
#define NEGV -10000.0f

typedef unsigned short ushortT;
typedef __attribute__((ext_vector_type(4))) float f32x4;
typedef __attribute__((ext_vector_type(8))) short short8;

// Opaque register pin: value becomes the result of an asm -> cannot be
// rematerialized from memory by the register allocator.
#define PINV(x) asm volatile("" : "+v"(x))

__device__ __forceinline__ float sigf_slow(float x) { return 1.0f / (1.0f + expf(-x)); }
__device__ __forceinline__ float fsig(float x) { return 1.0f / (1.0f + __expf(-x)); }
__device__ __forceinline__ float ftanh(float x) { return 1.0f - 2.0f / (1.0f + __expf(2.0f * x)); }
__device__ __forceinline__ ushortT f2bf(float f) {
    unsigned int u = __float_as_uint(f);
    u += 0x7fffu + ((u >> 16) & 1u);
    return (ushortT)(u >> 16);
}
__device__ __forceinline__ float bf2f(unsigned int bits16) {
    return __uint_as_float(bits16 << 16);
}

// ===========================================================================
// FAST PATH
// ===========================================================================

__global__ __launch_bounds__(256) void k_cvtw(
    const float* __restrict__ whh_f, const float* __restrict__ whh_b,
    const float* __restrict__ wih_f, const float* __restrict__ wih_b,
    ushortT* __restrict__ whh16, ushortT* __restrict__ wih16)
{
    int idx = blockIdx.x * 256 + threadIdx.x;     // < 262144
    const float* s; ushortT* d;
    switch (blockIdx.y) {
        case 0: s = whh_f; d = whh16;            break;
        case 1: s = whh_b; d = whh16 + 262144;   break;
        case 2: s = wih_f; d = wih16;            break;
        default: s = wih_b; d = wih16 + 262144;  break;
    }
    d[idx] = f2bf(s[idx]);
}

__global__ __launch_bounds__(1024) void k_bias(
    const float* __restrict__ bih_f, const float* __restrict__ bhh_f,
    const float* __restrict__ bih_b, const float* __restrict__ bhh_b,
    float* __restrict__ biasc)
{
    int n = threadIdx.x;
    if (blockIdx.x == 0) biasc[n] = bih_f[n] + bhh_f[n];
    else                 biasc[1024 + n] = bih_b[n] + bhh_b[n];
}

// K-gin: gin[dirg][t][col*16 + row] = x_t @ Wih^T + bias  (bf16 MFMA)
//   WG = (group, t-tile, dir*2+half). half owns 512 gate-cols ->
//   bfr[4][8] = 128 VGPR, PINNED resident, reused for 16 timesteps.
__global__
__attribute__((amdgpu_flat_work_group_size(512, 512)))
__attribute__((amdgpu_waves_per_eu(2, 2)))
void k_gin_mfma(
    const int* __restrict__ sent, const int* __restrict__ lens,
    const float* __restrict__ emb, const ushortT* __restrict__ wih16,
    const float* __restrict__ biasc, float* __restrict__ gin,
    int chunk_start, int CH)
{
    const int g = blockIdx.x, tsub = blockIdx.y;
    const int dir = blockIdx.z >> 1, half = blockIdx.z & 1;
    const int gmax = lens[g * 16];
    const int tt0 = tsub * 16;
    if (chunk_start + tt0 >= gmax) return;

    const int tid = threadIdx.x;
    const int w = tid >> 6, l = tid & 63, lr = l & 15, lg = l >> 4;

    __shared__ char x_raw[16 * 512];

    // resident weights: 4 gates x 8 k-tiles for this lane's unit column
    const int ucol = half * 128 + w * 16 + lr;
    short8 bfr[4][8];
    float bias_l[4];
    const ushortT* wsrc = wih16 + dir * 262144;
#pragma unroll
    for (int nt = 0; nt < 4; ++nt) {
        int col = nt * 256 + ucol;
        bias_l[nt] = biasc[dir * 1024 + col];
#pragma unroll
        for (int kt = 0; kt < 8; ++kt)
            bfr[nt][kt] = *(const short8*)(wsrc + (size_t)col * 256 + kt * 32 + lg * 8);
    }
#pragma unroll
    for (int nt = 0; nt < 4; ++nt) {
        PINV(bias_l[nt]);
#pragma unroll
        for (int kt = 0; kt < 8; ++kt) PINV(bfr[nt][kt]);
    }

    const int srow = tid >> 5, sseg = tid & 31;
    const int slen = lens[g * 16 + srow];
    const int sb = (g * 16 + srow) * 512;

    for (int i = 0; i < 16; ++i) {
        int tg = chunk_start + tt0 + i;
        if (tg >= gmax) break;

        // stage x_t: 16 rows x 256 fp32 -> bf16, swizzled LDS
        int tsrc = dir ? (slen - 1 - tg) : tg;
        if (tsrc < 0) tsrc = 0;
        if (tsrc > 511) tsrc = 511;
        int tok = sent[sb + tsrc];
        const float* es = emb + (size_t)tok * 256 + sseg * 8;
        float4 e0 = *(const float4*)es;
        float4 e1 = *(const float4*)(es + 4);
        short8 xv;
        xv[0] = (short)f2bf(e0.x); xv[1] = (short)f2bf(e0.y);
        xv[2] = (short)f2bf(e0.z); xv[3] = (short)f2bf(e0.w);
        xv[4] = (short)f2bf(e1.x); xv[5] = (short)f2bf(e1.y);
        xv[6] = (short)f2bf(e1.z); xv[7] = (short)f2bf(e1.w);
        int sa = (srow * 512 + sseg * 16) ^ ((srow & 7) << 4);
        *(short8*)&x_raw[sa] = xv;
        __syncthreads();

        short8 af[8];
#pragma unroll
        for (int kt = 0; kt < 8; ++kt) {
            int a = (lr * 512 + kt * 64 + lg * 16) ^ ((lr & 7) << 4);
            af[kt] = *(const short8*)&x_raw[a];
        }
        f32x4 acc[4];
#pragma unroll
        for (int nt = 0; nt < 4; ++nt) {
            acc[nt][0] = bias_l[nt]; acc[nt][1] = bias_l[nt];
            acc[nt][2] = bias_l[nt]; acc[nt][3] = bias_l[nt];
        }
#pragma unroll
        for (int kt = 0; kt < 8; ++kt)
#pragma unroll
            for (int nt = 0; nt < 4; ++nt)
                acc[nt] = __builtin_amdgcn_mfma_f32_16x16x32_bf16(af[kt], bfr[nt][kt], acc[nt], 0, 0, 0);

        float* ginp = gin + ((size_t)((dir * 4 + g) * CH + (tt0 + i))) * 16384;
#pragma unroll
        for (int nt = 0; nt < 4; ++nt)
            *(f32x4*)(ginp + (nt * 256 + ucol) * 16 + lg * 4) = acc[nt];
        __syncthreads();
    }
}

// K-rec: weights fully VGPR-resident (PINNED) across 2 CUs per (group,dir).
//   WG = (g, dir, half). Per step the halves exchange h-halves via an LLC
//   mailbox (agent-scope atomics + monotonic flags).
__global__
__attribute__((amdgpu_flat_work_group_size(512, 512)))
__attribute__((amdgpu_waves_per_eu(2, 2)))
void k_rec_mfma(
    const int* __restrict__ lens, const ushortT* __restrict__ whh16,
    const float* __restrict__ gin, ushortT* __restrict__ hout,
    ushortT* __restrict__ st_h, float* __restrict__ st_c,
    ushortT* __restrict__ hex, unsigned int* __restrict__ flags,
    int chunk_start, int CH)
{
    const int g = blockIdx.x, dir = blockIdx.y, half = blockIdx.z;
    const int gmax = lens[g * 16];
    const int nsteps = min(CH, gmax - chunk_start);
    if (nsteps <= 0) return;

    const int tid = threadIdx.x;
    const int w = tid >> 6, l = tid & 63, lr = l & 15, lg = l >> 4;

    __shared__ char h_s[2][8192];   // [buf][row*512B + unit*2B], XOR-swizzled

    int lenr[4];
#pragma unroll
    for (int r = 0; r < 4; ++r) lenr[r] = lens[g * 16 + lg * 4 + r];

    // resident weights: 4 gates x 8 k-tiles for this lane's unit, PINNED
    const int ucol = half * 128 + w * 16 + lr;
    short8 bfr[4][8];
    {
        const ushortT* wsrc = whh16 + dir * 262144;
#pragma unroll
        for (int nt = 0; nt < 4; ++nt) {
            const ushortT* wp = wsrc + (size_t)(nt * 256 + ucol) * 256 + lg * 8;
#pragma unroll
            for (int kt = 0; kt < 8; ++kt)
                bfr[nt][kt] = *(const short8*)(wp + kt * 32);
        }
    }
#pragma unroll
    for (int nt = 0; nt < 4; ++nt)
#pragma unroll
        for (int kt = 0; kt < 8; ++kt) PINV(bfr[nt][kt]);

    // state init / restore
    float c[4];
    if (chunk_start == 0) {
#pragma unroll
        for (int r = 0; r < 4; ++r) c[r] = 0.0f;
        for (int i = tid; i < 2048; i += 512) ((int*)h_s[0])[i] = 0;
    } else {
        const float* cs = st_c + ((size_t)((dir * 4 + g) * 2 + half)) * 2048 + tid * 4;
#pragma unroll
        for (int r = 0; r < 4; ++r) c[r] = cs[r];
        const int* hs = (const int*)st_h + (dir * 4 + g) * 2048;
        for (int i = tid; i < 2048; i += 512) ((int*)h_s[0])[i] = hs[i];
    }
    __syncthreads();

    // exchange constants
    unsigned int* exu = (unsigned int*)(hex + (dir * 4 + g) * 8192);  // 2 slots x 2048 uints
    unsigned int* flagMe = flags + (dir * 4 + g) * 2 + half;
    unsigned int* flagPeer = flags + (dir * 4 + g) * 2 + (half ^ 1);

    int own_lds[2], own_gid[2], peer_lds[2], peer_gid[2];
#pragma unroll
    for (int s2 = 0; s2 < 2; ++s2) {
        int i = tid * 2 + s2;
        int row = i >> 6, j = i & 63;
        int mu = half * 128 + j * 2;
        own_lds[s2] = (row * 512 + mu * 2) ^ ((row & 7) << 4);
        own_gid[s2] = row * 128 + half * 64 + j;
        int pu = (half ^ 1) * 128 + j * 2;
        peer_lds[s2] = (row * 512 + pu * 2) ^ ((row & 7) << 4);
        peer_gid[s2] = row * 128 + (half ^ 1) * 64 + j;
    }

    const float* ginp = gin + ((size_t)((dir * 4 + g) * CH)) * 16384;
    int p = 0;
    for (int tt = 0; tt < nsteps; ++tt) {
        const int t_glob = chunk_start + tt;

        // gin (input projection) for my 4 gate-cols; consumed in pointwise
        f32x4 gv[4];
#pragma unroll
        for (int nt = 0; nt < 4; ++nt)
            gv[nt] = *(const f32x4*)(ginp + (size_t)tt * 16384 + (nt * 256 + ucol) * 16 + lg * 4);

        // h @ Whh^T on resident weights
        const char* hb = h_s[p];
        f32x4 acc[4];
#pragma unroll
        for (int nt = 0; nt < 4; ++nt) { acc[nt][0] = 0.f; acc[nt][1] = 0.f; acc[nt][2] = 0.f; acc[nt][3] = 0.f; }
#pragma unroll
        for (int kt = 0; kt < 8; ++kt) {
            int a_ = (lr * 512 + kt * 64 + lg * 16) ^ ((lr & 7) << 4);
            short8 af = *(const short8*)&hb[a_];
#pragma unroll
            for (int nt = 0; nt < 4; ++nt)
                acc[nt] = __builtin_amdgcn_mfma_f32_16x16x32_bf16(af, bfr[nt][kt], acc[nt], 0, 0, 0);
        }

        // pointwise cell (lane has all 4 gates of unit ucol, rows lg*4+r)
        char* hw = h_s[p ^ 1];
#pragma unroll
        for (int r = 0; r < 4; ++r) {
            float i_ = acc[0][r] + gv[0][r];
            float f_ = acc[1][r] + gv[1][r];
            float g_ = acc[2][r] + gv[2][r];
            float o_ = acc[3][r] + gv[3][r];
            float cn = fsig(f_) * c[r] + fsig(i_) * ftanh(g_);
            float hn = fsig(o_) * ftanh(cn);
            c[r] = cn;
            ushortT hb16 = f2bf(hn);
            int row = lg * 4 + r;
            int a_ = (row * 512 + ucol * 2) ^ ((row & 7) << 4);
            *(ushortT*)&hw[a_] = hb16;
            if (t_glob < lenr[r]) {
                int tp = dir ? (lenr[r] - 1 - t_glob) : t_glob;
                hout[((size_t)((g * 16 + row) * 512 + tp)) * 512 + dir * 256 + ucol] = hb16;
            }
        }
        __syncthreads();   // own half of h(t+1) complete in LDS

        // publish own half to LLC mailbox
        unsigned int* exs = exu + ((t_glob + 1) & 1) * 2048;
#pragma unroll
        for (int s2 = 0; s2 < 2; ++s2) {
            unsigned int v = *(const unsigned int*)&hw[own_lds[s2]];
            __hip_atomic_store(&exs[own_gid[s2]], v, __ATOMIC_RELAXED, __HIP_MEMORY_SCOPE_AGENT);
        }
        __syncthreads();   // drains vmcnt -> all stores acked at LLC

        if (tid == 0) {
            __hip_atomic_store(flagMe, (unsigned int)(t_glob + 1), __ATOMIC_RELEASE, __HIP_MEMORY_SCOPE_AGENT);
            int guard = 0;
            while (__hip_atomic_load(flagPeer, __ATOMIC_RELAXED, __HIP_MEMORY_SCOPE_AGENT) < (unsigned int)(t_glob + 1)
                   && ++guard < (1 << 16)) {}
        }
        __syncthreads();

        // fetch peer half into LDS
#pragma unroll
        for (int s2 = 0; s2 < 2; ++s2) {
            unsigned int v = __hip_atomic_load(&exs[peer_gid[s2]], __ATOMIC_RELAXED, __HIP_MEMORY_SCOPE_AGENT);
            *(unsigned int*)&hw[peer_lds[s2]] = v;
        }
        __syncthreads();
        p ^= 1;
    }

    // save state
    float* cs = st_c + ((size_t)((dir * 4 + g) * 2 + half)) * 2048 + tid * 4;
#pragma unroll
    for (int r = 0; r < 4; ++r) cs[r] = c[r];
    if (half == 0) {
        int* hs = (int*)st_h + (dir * 4 + g) * 2048;
        for (int i = tid; i < 2048; i += 512) hs[i] = ((int*)h_s[p])[i];
    }
}

// K-scores: scores[b,t,:] = h[b,t,:] (bf16) @ w_out^T + b_out  (t < len)
__global__ __launch_bounds__(256) void k_scores_bf(
    const int* __restrict__ lens, const ushortT* __restrict__ hout,
    const float* __restrict__ w_out, const float* __restrict__ b_out,
    float* __restrict__ scores)
{
    const int b = blockIdx.y;
    const int t0 = blockIdx.x * 32;
    const int len = lens[b];
    if (t0 >= len) return;

    __shared__ float w_s[20 * 513];
    __shared__ float row_s[512];
    __shared__ float part_s[20][9];
    __shared__ float bo_s[20];

    const int tid = threadIdx.x;
    for (int e = tid; e < 20 * 512; e += 256) w_s[(e >> 9) * 513 + (e & 511)] = w_out[e];
    if (tid < 20) bo_s[tid] = b_out[tid];
    __syncthreads();

    const int tend = min(t0 + 32, len);
    const int tag = tid >> 3, sl = tid & 7;
    for (int t = t0; t < tend; ++t) {
        const ushortT* hr = hout + ((size_t)(b * 512 + t)) * 512;
        unsigned int v = ((const unsigned int*)hr)[tid];
        row_s[tid * 2] = bf2f(v & 0xffffu);
        row_s[tid * 2 + 1] = bf2f(v >> 16);
        __syncthreads();
        if (tid < 160) {
            float s = 0.0f;
#pragma unroll 8
            for (int j = 0; j < 64; ++j) {
                int k = sl + (((j + tag) & 63) << 3);
                s = fmaf(w_s[tag * 513 + k], row_s[k], s);
            }
            part_s[tag][sl] = s;
        }
        __syncthreads();
        if (tid < 20) {
            float s = bo_s[tid];
#pragma unroll
            for (int j = 0; j < 8; ++j) s += part_s[tid][j];
            scores[((size_t)(b * 512 + t)) * 20 + tid] = s;
        }
        __syncthreads();
    }
}

__global__ __launch_bounds__(64) void k_viterbi_s(
    const int* __restrict__ lens, const float* __restrict__ scores,
    const float* __restrict__ trans, float* __restrict__ out)
{
    const int b = blockIdx.x;
    const int lane = threadIdx.x;
    const int len = lens[b];

    __shared__ float tr_s[20][21];
    __shared__ float fv_s[20];
    __shared__ float term_s[20];
    __shared__ unsigned char bp_s[512][20];
    __shared__ unsigned char path_s[512];

    for (int e = lane; e < 400; e += 64) tr_s[e / 20][e % 20] = trans[e];
    if (lane < 20) fv_s[lane] = (lane == TAG_START) ? 0.0f : NEGV;
    __syncthreads();

    const float* sc = scores + ((size_t)(b << 9)) * 20;
    for (int t = 0; t < len; ++t) {
        float m = 0.0f; int arg = 0;
        if (lane < 20) {
            m = fv_s[0] + tr_s[lane][0]; arg = 0;
#pragma unroll
            for (int k = 1; k < 20; ++k) {
                float v = fv_s[k] + tr_s[lane][k];
                if (v > m) { m = v; arg = k; }
            }
            m += sc[t * 20 + lane];
        }
        __syncthreads();
        if (lane < 20) { fv_s[lane] = m; bp_s[t][lane] = (unsigned char)arg; }
        __syncthreads();
    }

    if (lane < 20) term_s[lane] = fv_s[lane] + tr_s[TAG_STOP][lane];
    __syncthreads();

    if (lane == 0) {
        float m = term_s[0]; int arg = 0;
        for (int k = 1; k < 20; ++k) if (term_s[k] > m) { m = term_s[k]; arg = k; }
        out[b] = m;
        int cur = arg;
        path_s[len - 1] = (unsigned char)cur;
        for (int j = len - 1; j >= 1; --j) {
            cur = bp_s[j][cur];
            path_s[j - 1] = (unsigned char)cur;
        }
    }
    __syncthreads();

    float* po = out + NB + ((size_t)b << 9);
    for (int p = lane; p < NL; p += 64) po[p] = (p < len) ? (float)path_s[p] : 0.0f;
}

// ===========================================================================
// FALLBACK PATH (round-2 proven)
// ===========================================================================
__global__ __launch_bounds__(256) void k_transpose_fb(
    const float* __restrict__ whh_f, const float* __restrict__ whh_b,
    const float* __restrict__ wih_f, const float* __restrict__ wih_b,
    float* __restrict__ thh_f, float* __restrict__ thh_b,
    float* __restrict__ tih_f, float* __restrict__ tih_b)
{
    int e = blockIdx.x * 256 + threadIdx.x;
    const float* wm; float* wt;
    switch (blockIdx.y) {
        case 0: wm = whh_f; wt = thh_f; break;
        case 1: wm = whh_b; wt = thh_b; break;
        case 2: wm = wih_f; wt = tih_f; break;
        default: wm = wih_b; wt = tih_b; break;
    }
    int n = e >> 8, k = e & 255;
    wt[k * 1024 + n] = wm[e];
}

__global__ __launch_bounds__(1024) void k_rec_fb(
    const int* __restrict__ sent, const int* __restrict__ lens,
    const float* __restrict__ emb,
    const float* __restrict__ thh_f, const float* __restrict__ thh_b,
    const float* __restrict__ tih_f, const float* __restrict__ tih_b,
    const float* __restrict__ b_ih_f, const float* __restrict__ b_hh_f,
    const float* __restrict__ b_ih_b, const float* __restrict__ b_hh_b,
    const float* __restrict__ w_out,
    float* __restrict__ sc_f, float* __restrict__ sc_b)
{
    const int b = blockIdx.x, dir = blockIdx.y;
    const int len = lens[b];
    const int n = threadIdx.x;
    const float* Whh = dir ? thh_b : thh_f;
    const float* Wih = dir ? tih_b : tih_f;
    const float* bi = dir ? b_ih_b : b_ih_f;
    const float* bh = dir ? b_hh_b : b_hh_f;
    float* scout = dir ? sc_b : sc_f;

    __shared__ float x_s[256];
    __shared__ float h_s[256];
    __shared__ float g_s[1024];
    __shared__ float bias_s[1024];
    __shared__ float wout_s[20 * 257];
    __shared__ float part_s[20][8];

    bias_s[n] = bi[n] + bh[n];
    for (int e = n; e < 20 * 256; e += 1024)
        wout_s[(e >> 8) * 257 + (e & 255)] = w_out[(e >> 8) * 512 + dir * 256 + (e & 255)];
    if (n < 256) h_s[n] = 0.0f;
    float c = 0.0f;
    __syncthreads();

    const int sbase = b << 9;
    for (int t = 0; t < len; ++t) {
        if (n < 256) {
            int ti = dir ? (len - 1 - t) : t;
            int tok = sent[sbase + ti];
            x_s[n] = emb[(size_t)tok * NE + n];
        }
        __syncthreads();
        float acc = bias_s[n];
        const float* wi = Wih + n;
        const float* wh = Whh + n;
#pragma unroll 8
        for (int k = 0; k < 256; ++k) {
            acc = fmaf(wh[(size_t)(k << 10)], h_s[k], acc);
            acc = fmaf(wi[(size_t)(k << 10)], x_s[k], acc);
        }
        g_s[n] = acc;
        __syncthreads();
        if (n < 256) {
            float ig = g_s[n], fg = g_s[n + 256], gg = g_s[n + 512], og = g_s[n + 768];
            float cn = sigf_slow(fg) * c + sigf_slow(ig) * tanhf(gg);
            float hn = sigf_slow(og) * tanhf(cn);
            c = cn; h_s[n] = hn;
        }
        __syncthreads();
        if (n < 160) {
            const int tag = n >> 3, sl = n & 7;
            const float* wrow = wout_s + tag * 257;
            float s = 0.0f;
#pragma unroll 8
            for (int j = 0; j < 32; ++j) { int k = sl + (j << 3); s = fmaf(wrow[k], h_s[k], s); }
            part_s[tag][sl] = s;
        }
        __syncthreads();
        if (n < 20) {
            float s = part_s[n][0];
#pragma unroll
            for (int j = 1; j < 8; ++j) s += part_s[n][j];
            int tp = dir ? (len - 1 - t) : t;
            scout[(size_t)(sbase + tp) * 20 + n] = s;
        }
    }
}

__global__ __launch_bounds__(64) void k_viterbi_fb(
    const int* __restrict__ lens,
    const float* __restrict__ sc_f, const float* __restrict__ sc_b,
    const float* __restrict__ b_out, const float* __restrict__ trans,
    float* __restrict__ out)
{
    const int b = blockIdx.x;
    const int lane = threadIdx.x;
    const int len = lens[b];

    __shared__ float tr_s[20][21];
    __shared__ float fv_s[20];
    __shared__ float term_s[20];
    __shared__ float bo_s[20];
    __shared__ unsigned char bp_s[512][20];
    __shared__ unsigned char path_s[512];

    for (int e = lane; e < 400; e += 64) tr_s[e / 20][e % 20] = trans[e];
    if (lane < 20) { fv_s[lane] = (lane == TAG_START) ? 0.0f : NEGV; bo_s[lane] = b_out[lane]; }
    __syncthreads();

    const size_t sb = (size_t)(b << 9) * 20;
    for (int t = 0; t < len; ++t) {
        float m = 0.0f; int arg = 0;
        if (lane < 20) {
            m = fv_s[0] + tr_s[lane][0]; arg = 0;
#pragma unroll
            for (int k = 1; k < 20; ++k) {
                float v = fv_s[k] + tr_s[lane][k];
                if (v > m) { m = v; arg = k; }
            }
            m += sc_f[sb + t * 20 + lane] + sc_b[sb + t * 20 + lane] + bo_s[lane];
        }
        __syncthreads();
        if (lane < 20) { fv_s[lane] = m; bp_s[t][lane] = (unsigned char)arg; }
        __syncthreads();
    }
    if (lane < 20) term_s[lane] = fv_s[lane] + tr_s[TAG_STOP][lane];
    __syncthreads();
    if (lane == 0) {
        float m = term_s[0]; int arg = 0;
        for (int k = 1; k < 20; ++k) if (term_s[k] > m) { m = term_s[k]; arg = k; }
        out[b] = m;
        int cur = arg;
        path_s[len - 1] = (unsigned char)cur;
        for (int j = len - 1; j >= 1; --j) { cur = bp_s[j][cur]; path_s[j - 1] = (unsigned char)cur; }
    }
    __syncthreads();
    float* po = out + NB + ((size_t)b << 9);
    for (int p = lane; p < NL; p += 64) po[p] = (p < len) ? (float)path_s[p] : 0.0f;
}

// ===========================================================================
extern "C" void kernel_launch(void* const* d_in, const int* in_sizes, int n_in,
                              void* d_out, int out_size, void* d_ws, size_t ws_size,
                              hipStream_t stream)
{
    const int*   sent   = (const int*)d_in[0];
    const int*   lens   = (const int*)d_in[1];
    const float* emb    = (const float*)d_in[2];
    const float* w_ih_f = (const float*)d_in[3];
    const float* w_hh_f = (const float*)d_in[4];
    const float* b_ih_f = (const float*)d_in[5];
    const float* b_hh_f = (const float*)d_in[6];
    const float* w_ih_b = (const float*)d_in[7];
    const float* w_hh_b = (const float*)d_in[8];
    const float* b_ih_b = (const float*)d_in[9];
    const float* b_hh_b = (const float*)d_in[10];
    const float* w_out  = (const float*)d_in[11];
    const float* b_out  = (const float*)d_in[12];
    const float* trans  = (const float*)d_in[13];
    float* out = (float*)d_out;

    char* w = (char*)d_ws;
    // layout:
    //  whh16   @ 0        (1 MB)     wih16 @ 1048576 (1 MB)
    //  biasc   @ 2097152  (8 KB)     st_h  @ 2105344 (64 KB)
    //  st_c    @ 2170880  (128 KB)   hex   @ 2301952 (128 KB)
    //  flags   @ 2433024  (4 KB)     scores@ 2437120 (2.5 MB)
    //  hout    @ 5058560  (32 MB)    gin   @ 38612992 (CH*512 KB)
    const size_t base = 38612992;
    int CH = 0;
    const int chs[6] = {512, 256, 192, 128, 64, 32};
    for (int i = 0; i < 6; ++i)
        if (base + (size_t)chs[i] * 524288 <= ws_size) { CH = chs[i]; break; }

    if (CH) {
        ushortT* whh16 = (ushortT*)(w);
        ushortT* wih16 = (ushortT*)(w + 1048576);
        float*   biasc = (float*)(w + 2097152);
        ushortT* st_h  = (ushortT*)(w + 2105344);
        float*   st_c  = (float*)(w + 2170880);
        ushortT* hex   = (ushortT*)(w + 2301952);
        unsigned int* flags = (unsigned int*)(w + 2433024);
        float*   scores= (float*)(w + 2437120);
        ushortT* hout  = (ushortT*)(w + 5058560);
        float*   gin   = (float*)(w + base);

        hipMemsetAsync(flags, 0, 4096, stream);
        k_cvtw<<<dim3(1024, 4), 256, 0, stream>>>(w_hh_f, w_hh_b, w_ih_f, w_ih_b, whh16, wih16);
        k_bias<<<2, 1024, 0, stream>>>(b_ih_f, b_hh_f, b_ih_b, b_hh_b, biasc);

        for (int cs = 0; cs < NL; cs += CH) {
            k_gin_mfma<<<dim3(4, CH / 16, 4), 512, 0, stream>>>(
                sent, lens, emb, wih16, biasc, gin, cs, CH);
            k_rec_mfma<<<dim3(4, 2, 2), 512, 0, stream>>>(
                lens, whh16, gin, hout, st_h, st_c, hex, flags, cs, CH);
        }
        k_scores_bf<<<dim3(16, 64), 256, 0, stream>>>(lens, hout, w_out, b_out, scores);
        k_viterbi_s<<<64, 64, 0, stream>>>(lens, scores, trans, out);
    } else {
        float* ws2   = (float*)d_ws;
        float* thh_f = ws2;
        float* thh_b = thh_f + 262144;
        float* tih_f = thh_b + 262144;
        float* tih_b = tih_f + 262144;
        float* sc_f  = tih_b + 262144;
        float* sc_b  = sc_f + (size_t)NB * NL * NT;

        k_transpose_fb<<<dim3(1024, 4), 256, 0, stream>>>(
            w_hh_f, w_hh_b, w_ih_f, w_ih_b, thh_f, thh_b, tih_f, tih_b);
        k_rec_fb<<<dim3(NB, 2), 1024, 0, stream>>>(
            sent, lens, emb, thh_f, thh_b, tih_f, tih_b,
            b_ih_f, b_hh_f, b_ih_b, b_hh_b, w_out, sc_f, sc_b);
        k_viterbi_fb<<<NB, 64, 0, stream>>>(lens, sc_f, sc_b, b_out, trans, out);
    }
}